// Round 1
// baseline (333.042 us; speedup 1.0000x reference)
//
#include <hip/hip_runtime.h>
#include <hip/hip_bf16.h>
#include <math.h>

typedef __bf16 bf16x8 __attribute__((ext_vector_type(8)));
typedef float f32x4 __attribute__((ext_vector_type(4)));

#define QSCALE 0.08838834764831845f

// ---------------- kernel 1: convert + concat weights to bf16 ----------------
__global__ __launch_bounds__(256) void k_convw(const float* __restrict__ wqk,
                                               const float* __restrict__ wv,
                                               __hip_bfloat16* __restrict__ wall) {
  int i = blockIdx.x * 256 + threadIdx.x;
  if (i >= 1536 * 512) return;
  float v = (i < 1024 * 512) ? wqk[i] : wv[i - 1024 * 512];
  wall[i] = __float2bfloat16(v);
}

// ---------------- kernel 2: transpose + convert featuremap -> [B][L][C] bf16 ----------------
__global__ __launch_bounds__(256) void k_tfm(const float* __restrict__ fm,
                                             __hip_bfloat16* __restrict__ fmt) {
  __shared__ float t[64][65];
  int lt = blockIdx.x, ct = blockIdx.y, b = blockIdx.z;
  int tid = threadIdx.x;
  const float* src = fm + ((size_t)b * 512 + ct * 64) * 1024 + lt * 64;
#pragma unroll
  for (int i = 0; i < 16; ++i) {
    int idx = i * 256 + tid;
    int r = idx >> 6, cl = idx & 63;
    t[r][cl] = src[(size_t)r * 1024 + cl];
  }
  __syncthreads();
  __hip_bfloat16* dst = fmt + ((size_t)b * 1024 + lt * 64) * 512 + ct * 64;
#pragma unroll
  for (int i = 0; i < 16; ++i) {
    int idx = i * 256 + tid;
    int r = idx >> 6, cc = idx & 63;
    dst[(size_t)r * 512 + cc] = __float2bfloat16(t[cc][r]);
  }
}

// ---------------- kernel 3: QKV projection GEMM ----------------
// C[l][o] = sum_c fmt[b][l][c] * wall[o][c];  M=1024(l), N=1536(o), K=512 per batch.
// Epilogue: o<512 -> Q[b][h][l][d]*scale ; o<1024 -> K[b][h][l][d] ; else V_t[b][h][d][l]
__global__ __launch_bounds__(256) void k_gemm(const __hip_bfloat16* __restrict__ fmt,
                                              const __hip_bfloat16* __restrict__ wall,
                                              __hip_bfloat16* __restrict__ Qb,
                                              __hip_bfloat16* __restrict__ Kb,
                                              __hip_bfloat16* __restrict__ Vt) {
  __shared__ char smem[32768];
  char* As = smem;
  char* Bs = smem + 16384;
  int bm = blockIdx.x, bn = blockIdx.y, b = blockIdx.z;
  int tid = threadIdx.x;
  int lane = tid & 63, wave = tid >> 6;
  int wr = wave >> 1, wc = wave & 1;
  const __hip_bfloat16* Ag = fmt + ((size_t)b * 1024 + bm * 128) * 512;
  const __hip_bfloat16* Bg = wall + (size_t)bn * 128 * 512;

  f32x4 acc[4][4] = {};
  uint4 ra[4], rb[4];
#pragma unroll
  for (int i = 0; i < 4; ++i) {
    int chunk = i * 256 + tid;
    int row = chunk >> 3, c16 = chunk & 7;
    ra[i] = *(const uint4*)(Ag + (size_t)row * 512 + c16 * 8);
    rb[i] = *(const uint4*)(Bg + (size_t)row * 512 + c16 * 8);
  }
  for (int kb = 0; kb < 8; ++kb) {
    __syncthreads();
#pragma unroll
    for (int i = 0; i < 4; ++i) {
      int chunk = i * 256 + tid;
      int row = chunk >> 3, c16 = chunk & 7;
      int off = row * 128 + ((c16 * 16) ^ ((row & 7) << 4));
      *(uint4*)(As + off) = ra[i];
      *(uint4*)(Bs + off) = rb[i];
    }
    __syncthreads();
    if (kb < 7) {
#pragma unroll
      for (int i = 0; i < 4; ++i) {
        int chunk = i * 256 + tid;
        int row = chunk >> 3, c16 = chunk & 7;
        ra[i] = *(const uint4*)(Ag + (size_t)row * 512 + (kb + 1) * 64 + c16 * 8);
        rb[i] = *(const uint4*)(Bg + (size_t)row * 512 + (kb + 1) * 64 + c16 * 8);
      }
    }
#pragma unroll
    for (int ks = 0; ks < 2; ++ks) {
      int kcol = ks * 64 + ((lane >> 4) << 4);
      bf16x8 af[4], bfr[4];
#pragma unroll
      for (int m = 0; m < 4; ++m) {
        int row = wr * 64 + m * 16 + (lane & 15);
        af[m] = *(const bf16x8*)(As + row * 128 + (kcol ^ ((row & 7) << 4)));
      }
#pragma unroll
      for (int n = 0; n < 4; ++n) {
        int row = wc * 64 + n * 16 + (lane & 15);
        bfr[n] = *(const bf16x8*)(Bs + row * 128 + (kcol ^ ((row & 7) << 4)));
      }
#pragma unroll
      for (int m = 0; m < 4; ++m)
#pragma unroll
        for (int n = 0; n < 4; ++n)
          acc[m][n] = __builtin_amdgcn_mfma_f32_16x16x32_bf16(af[m], bfr[n], acc[m][n], 0, 0, 0);
    }
  }
  int otype = bn >> 2;  // 0=q, 1=k, 2=v (N tiles of 128, 4 per type)
#pragma unroll
  for (int m = 0; m < 4; ++m) {
#pragma unroll
    for (int n = 0; n < 4; ++n) {
      int l = bm * 128 + wr * 64 + m * 16 + ((lane >> 4) << 2);
      int o = (bn & 3) * 128 + wc * 64 + n * 16 + (lane & 15);
      int head = o >> 7, d = o & 127;
      f32x4 v = acc[m][n];
      if (otype == 0) {
        __hip_bfloat16* p = Qb + (((size_t)(b * 4 + head) * 1024) + l) * 128 + d;
#pragma unroll
        for (int r = 0; r < 4; ++r) p[(size_t)r * 128] = __float2bfloat16(v[r] * QSCALE);
      } else if (otype == 1) {
        __hip_bfloat16* p = Kb + (((size_t)(b * 4 + head) * 1024) + l) * 128 + d;
#pragma unroll
        for (int r = 0; r < 4; ++r) p[(size_t)r * 128] = __float2bfloat16(v[r]);
      } else {
        __hip_bfloat16* p = Vt + (((size_t)(b * 4 + head) * 128) + d) * 1024 + l;
#pragma unroll
        for (int r = 0; r < 4; ++r) p[r] = __float2bfloat16(v[r]);
      }
    }
  }
}

// ---------------- kernel 4: bias tables  QRW/QRH[b][h][l][m] = q . rel[m] ----------------
__global__ __launch_bounds__(256) void k_bias(const __hip_bfloat16* __restrict__ Qb,
                                              const float* __restrict__ relw,
                                              const float* __restrict__ relh,
                                              float* __restrict__ QRW,
                                              float* __restrict__ QRH) {
  extern __shared__ float sh[];  // rws[63][129] | rhs[63][129] | qs[16][129]
  float* rws = sh;
  float* rhs = sh + 63 * 129;
  float* qs = sh + 2 * 63 * 129;
  int lg = blockIdx.x, bh = blockIdx.y;
  int tid = threadIdx.x;
  for (int i = tid; i < 63 * 128; i += 256) {
    int m = i >> 7, d = i & 127;
    rws[m * 129 + d] = relw[i];
    rhs[m * 129 + d] = relh[i];
  }
  const __hip_bfloat16* Qg = Qb + ((size_t)bh * 1024 + lg * 16) * 128;
  for (int i = tid; i < 16 * 128; i += 256) {
    qs[(i >> 7) * 129 + (i & 127)] = __bfloat162float(Qg[i]);
  }
  __syncthreads();
  int q = tid & 15, mb = tid >> 4;
  float accw[4] = {0.f, 0.f, 0.f, 0.f};
  float acch[4] = {0.f, 0.f, 0.f, 0.f};
  for (int d = 0; d < 128; ++d) {
    float qv = qs[q * 129 + d];
#pragma unroll
    for (int i = 0; i < 4; ++i) {
      int m = mb + i * 16;  // m=63 reads in-bounds garbage, discarded below
      accw[i] += qv * rws[m * 129 + d];
      acch[i] += qv * rhs[m * 129 + d];
    }
  }
  size_t obase = ((size_t)bh * 1024 + lg * 16 + q) * 64;
#pragma unroll
  for (int i = 0; i < 4; ++i) {
    int m = mb + i * 16;
    QRW[obase + m] = (m < 63) ? accw[i] : 0.f;
    QRH[obase + m] = (m < 63) ? acch[i] : 0.f;
  }
}

// ---------------- kernel 5: fused attention ----------------
// block = (b,h, 64 queries); 4 waves x 16 query rows; online softmax.
// logits[x,y] = q.k + QRW[x][cy-cx+31] + QRH[x][ry-rx+31]
// PV computed transposed: out_t[d][q] = V_t . P^T  -> coalesced fp32 stores.
__global__ __launch_bounds__(256) void k_attn(const __hip_bfloat16* __restrict__ Qb,
                                              const __hip_bfloat16* __restrict__ Kb,
                                              const __hip_bfloat16* __restrict__ Vt,
                                              const float* __restrict__ QRW,
                                              const float* __restrict__ QRH,
                                              float* __restrict__ out) {
  extern __shared__ char smem[];
  float* qrw_s = (float*)smem;               // [64][68] f32  17408 B
  float* qrh_s = (float*)(smem + 17408);     // [64][68] f32  17408 B
  char* kv = smem + 34816;                   // K tile [64][256B] (also Q stage) 16384 B
  char* vtl = smem + 51200;                  // V_t tile [128][128B] 16384 B
  char* pt = smem + 67584;                   // P [4 waves][16][128B] 8192 B
  float* rowstat = (float*)(smem + 75776);   // [4][16] f32

  int qt = blockIdx.x, bh = blockIdx.y;
  int b = bh >> 2, h = bh & 3;
  int tid = threadIdx.x, lane = tid & 63, wave = tid >> 6;
  int g = lane >> 4, ln = lane & 15;
  int q0 = qt * 64;
  size_t bhL = (size_t)bh * 1024;

  // stage Q tile (swizzled) into kv region
  const __hip_bfloat16* Qg = Qb + (bhL + q0) * 128;
#pragma unroll
  for (int i = 0; i < 4; ++i) {
    int chunk = i * 256 + tid;
    int row = chunk >> 4, c16 = chunk & 15;
    *(uint4*)(kv + row * 256 + ((c16 * 16) ^ ((row & 7) << 4))) =
        *(const uint4*)(Qg + row * 128 + c16 * 8);
  }
  // stage bias tables [64 q][64 m] with stride 68 (bank spread)
#pragma unroll
  for (int i = 0; i < 4; ++i) {
    int chunk = i * 256 + tid;
    int row = chunk >> 4, c16 = chunk & 15;
    *(uint4*)(qrw_s + row * 68 + c16 * 4) =
        *(const uint4*)(QRW + (bhL + q0 + row) * 64 + c16 * 4);
    *(uint4*)(qrh_s + row * 68 + c16 * 4) =
        *(const uint4*)(QRH + (bhL + q0 + row) * 64 + c16 * 4);
  }
  __syncthreads();
  bf16x8 qa[4];
  int qrow = wave * 16 + ln;
#pragma unroll
  for (int ks = 0; ks < 4; ++ks)
    qa[ks] = *(const bf16x8*)(kv + qrow * 256 + ((ks * 64 + (g << 4)) ^ ((qrow & 7) << 4)));

  f32x4 acc_o[8] = {};
  float mrow[4] = {-1e30f, -1e30f, -1e30f, -1e30f};
  float lrow[4] = {0.f, 0.f, 0.f, 0.f};
  char* pw = pt + wave * 2048;

  for (int kt = 0; kt < 16; ++kt) {
    __syncthreads();
    const __hip_bfloat16* Kg = Kb + (bhL + kt * 64) * 128;
#pragma unroll
    for (int i = 0; i < 4; ++i) {
      int chunk = i * 256 + tid;
      int row = chunk >> 4, c16 = chunk & 15;
      *(uint4*)(kv + row * 256 + ((c16 * 16) ^ ((row & 7) << 4))) =
          *(const uint4*)(Kg + row * 128 + c16 * 8);
    }
    const __hip_bfloat16* Vg = Vt + (size_t)bh * 128 * 1024 + kt * 64;
#pragma unroll
    for (int i = 0; i < 4; ++i) {
      int chunk = i * 256 + tid;
      int row = chunk >> 3, c16 = chunk & 7;
      *(uint4*)(vtl + row * 128 + ((c16 * 16) ^ ((row & 7) << 4))) =
          *(const uint4*)(Vg + (size_t)row * 1024 + c16 * 8);
    }
    __syncthreads();

    // S = Q K^T  (wave: 16 q rows x 64 keys)
    f32x4 s[4] = {};
#pragma unroll
    for (int ks = 0; ks < 4; ++ks) {
      int kcol = ks * 64 + (g << 4);
#pragma unroll
      for (int n = 0; n < 4; ++n) {
        int krow = n * 16 + ln;
        bf16x8 kf = *(const bf16x8*)(kv + krow * 256 + (kcol ^ ((krow & 7) << 4)));
        s[n] = __builtin_amdgcn_mfma_f32_16x16x32_bf16(qa[ks], kf, s[n], 0, 0, 0);
      }
    }
    // + relative position bias
#pragma unroll
    for (int n = 0; n < 4; ++n) {
      int key = kt * 64 + n * 16 + ln;
      int ry = key >> 5, cy = key & 31;
#pragma unroll
      for (int r = 0; r < 4; ++r) {
        int qloc = wave * 16 + g * 4 + r;
        int qg2 = q0 + qloc;
        s[n][r] += qrw_s[qloc * 68 + (cy - (qg2 & 31) + 31)] +
                   qrh_s[qloc * 68 + (ry - (qg2 >> 5) + 31)];
      }
    }
    // online softmax (rows live in regs as (g,r); reduce across 16-lane group)
    float mt[4];
#pragma unroll
    for (int r = 0; r < 4; ++r)
      mt[r] = fmaxf(fmaxf(s[0][r], s[1][r]), fmaxf(s[2][r], s[3][r]));
#pragma unroll
    for (int off = 1; off < 16; off <<= 1)
#pragma unroll
      for (int r = 0; r < 4; ++r) mt[r] = fmaxf(mt[r], __shfl_xor(mt[r], off, 64));
    float alpha[4];
#pragma unroll
    for (int r = 0; r < 4; ++r) {
      float mn = fmaxf(mrow[r], mt[r]);
      alpha[r] = __expf(mrow[r] - mn);
      mrow[r] = mn;
    }
    float rs[4] = {0.f, 0.f, 0.f, 0.f};
#pragma unroll
    for (int n = 0; n < 4; ++n)
#pragma unroll
      for (int r = 0; r < 4; ++r) {
        s[n][r] = __expf(s[n][r] - mrow[r]);
        rs[r] += s[n][r];
      }
#pragma unroll
    for (int off = 1; off < 16; off <<= 1)
#pragma unroll
      for (int r = 0; r < 4; ++r) rs[r] += __shfl_xor(rs[r], off, 64);
#pragma unroll
    for (int r = 0; r < 4; ++r) lrow[r] = lrow[r] * alpha[r] + rs[r];
    // broadcast alpha transposed (per-wave LDS, same-wave DS ordering)
    if (ln == 0) {
#pragma unroll
      for (int r = 0; r < 4; ++r) rowstat[wave * 16 + g * 4 + r] = alpha[r];
    }
    float alpha_t = rowstat[wave * 16 + ln];
#pragma unroll
    for (int mf = 0; mf < 8; ++mf) acc_o[mf] *= alpha_t;
    // write P (bf16, swizzled, per-wave region)
#pragma unroll
    for (int n = 0; n < 4; ++n)
#pragma unroll
      for (int r = 0; r < 4; ++r) {
        int prow = g * 4 + r;
        int pcb = (n * 16 + ln) * 2;
        *(__hip_bfloat16*)(pw + prow * 128 + (pcb ^ ((prow & 7) << 4))) =
            __float2bfloat16(s[n][r]);
      }
    // PV (transposed): acc_o[d][q] += V_t . P^T
#pragma unroll
    for (int ks2 = 0; ks2 < 2; ++ks2) {
      int kcb = ks2 * 64 + (g << 4);
      bf16x8 pb = *(const bf16x8*)(pw + ln * 128 + (kcb ^ ((ln & 7) << 4)));
#pragma unroll
      for (int mf = 0; mf < 8; ++mf) {
        int vrow = mf * 16 + ln;
        bf16x8 av = *(const bf16x8*)(vtl + vrow * 128 + (kcb ^ ((vrow & 7) << 4)));
        acc_o[mf] = __builtin_amdgcn_mfma_f32_16x16x32_bf16(av, pb, acc_o[mf], 0, 0, 0);
      }
    }
  }
  // final normalize + store (coalesced: 16 consecutive l per quarter-wave)
  if (ln == 0) {
#pragma unroll
    for (int r = 0; r < 4; ++r) rowstat[wave * 16 + g * 4 + r] = lrow[r];
  }
  float linv = 1.0f / rowstat[wave * 16 + ln];
  int qg2 = q0 + wave * 16 + ln;
#pragma unroll
  for (int mf = 0; mf < 8; ++mf) {
    int dbase = mf * 16 + g * 4;
#pragma unroll
    for (int r = 0; r < 4; ++r) {
      out[((size_t)(b * 512 + h * 128 + dbase + r)) * 1024 + qg2] = acc_o[mf][r] * linv;
    }
  }
}

extern "C" void kernel_launch(void* const* d_in, const int* in_sizes, int n_in,
                              void* d_out, int out_size, void* d_ws, size_t ws_size,
                              hipStream_t stream) {
  const float* fm = (const float*)d_in[0];
  const float* wqk = (const float*)d_in[1];
  const float* wv = (const float*)d_in[2];
  const float* relh = (const float*)d_in[3];
  const float* relw = (const float*)d_in[4];
  float* out = (float*)d_out;
  char* w = (char*)d_ws;

  __hip_bfloat16* fmt = (__hip_bfloat16*)w;                   // 16 MB  [B][L][C]
  __hip_bfloat16* wall = (__hip_bfloat16*)(w + 16777216);     // 1.5 MB [1536][512]
  __hip_bfloat16* Qb = (__hip_bfloat16*)(w + 18350080);       // 16 MB  [B][H][L][D] (scaled)
  __hip_bfloat16* Kb = (__hip_bfloat16*)(w + 35127296);       // 16 MB  [B][H][L][D]
  __hip_bfloat16* Vt = (__hip_bfloat16*)(w + 51904512);       // 16 MB  [B][H][D][L]
  float* QRW = (float*)(w + 68681728);                        // 16 MB  [B][H][L][64]
  float* QRH = (float*)(w + 85458944);                        // 16 MB  [B][H][L][64]

  k_convw<<<3072, 256, 0, stream>>>(wqk, wv, wall);
  k_tfm<<<dim3(16, 8, 16), 256, 0, stream>>>(fm, fmt);
  k_gemm<<<dim3(8, 12, 16), 256, 0, stream>>>(fmt, wall, Qb, Kb, Vt);
  k_bias<<<dim3(64, 64), 256, 73272 * sizeof(char) + 0, stream>>>(Qb, relw, relh, QRW, QRH);
  k_attn<<<dim3(16, 64), 256, 76032, stream>>>(Qb, Kb, Vt, QRW, QRH, out);
}

// Round 2
// 237.995 us; speedup vs baseline: 1.3994x; 1.3994x over previous
//
#include <hip/hip_runtime.h>
#include <hip/hip_bf16.h>
#include <math.h>

typedef __bf16 bf16x8 __attribute__((ext_vector_type(8)));
typedef float f32x4 __attribute__((ext_vector_type(4)));

#define QSCALE 0.08838834764831845f

static __device__ __forceinline__ unsigned short bits_bf16(float v) {
  __hip_bfloat16 h = __float2bfloat16(v);
  return *reinterpret_cast<unsigned short*>(&h);
}

// ---------------- kernel 1: convert weights + rel tables to bf16 ----------------
__global__ __launch_bounds__(256) void k_convw(const float* __restrict__ wqk,
                                               const float* __restrict__ wv,
                                               const float* __restrict__ relw,
                                               const float* __restrict__ relh,
                                               __hip_bfloat16* __restrict__ wall,
                                               __hip_bfloat16* __restrict__ relsb) {
  int i = blockIdx.x * 256 + threadIdx.x;
  if (i < 1536 * 512) {
    float v = (i < 1024 * 512) ? wqk[i] : wv[i - 1024 * 512];
    wall[i] = __float2bfloat16(v);
  } else {
    int j = i - 1536 * 512;  // 0..16383 : [2][64][128], row 63 of each table = 0
    int t = j >> 13, m = (j >> 7) & 63, d = j & 127;
    float v = (m < 63) ? (t ? relh[m * 128 + d] : relw[m * 128 + d]) : 0.f;
    relsb[j] = __float2bfloat16(v);
  }
}

// ---------------- kernel 2: transpose + convert featuremap -> [B][L][C] bf16 ----------------
__global__ __launch_bounds__(256) void k_tfm(const float* __restrict__ fm,
                                             __hip_bfloat16* __restrict__ fmt) {
  __shared__ float t[64][65];
  int lt = blockIdx.x, ct = blockIdx.y, b = blockIdx.z;
  int tid = threadIdx.x;
  const float* src = fm + ((size_t)b * 512 + ct * 64) * 1024 + lt * 64;
#pragma unroll
  for (int i = 0; i < 16; ++i) {
    int idx = i * 256 + tid;
    int r = idx >> 6, cl = idx & 63;
    t[r][cl] = src[(size_t)r * 1024 + cl];
  }
  __syncthreads();
  __hip_bfloat16* dst = fmt + ((size_t)b * 1024 + lt * 64) * 512 + ct * 64;
#pragma unroll
  for (int i = 0; i < 16; ++i) {
    int idx = i * 256 + tid;
    int r = idx >> 6, cc = idx & 63;
    dst[(size_t)r * 512 + cc] = __float2bfloat16(t[cc][r]);
  }
}

// ---------------- kernel 3: QKV projection GEMM ----------------
// C[l][o] = sum_c fmt[b][l][c] * wall[o][c];  M=1024(l), N=1536(o), K=512 per batch.
// Epilogue via LDS restaging -> fully coalesced 256B-row stores.
__global__ __launch_bounds__(256) void k_gemm(const __hip_bfloat16* __restrict__ fmt,
                                              const __hip_bfloat16* __restrict__ wall,
                                              __hip_bfloat16* __restrict__ Qb,
                                              __hip_bfloat16* __restrict__ Kb,
                                              __hip_bfloat16* __restrict__ Vt) {
  __shared__ char smem[32768];
  char* As = smem;
  char* Bs = smem + 16384;
  int bm = blockIdx.x, bn = blockIdx.y, b = blockIdx.z;
  int tid = threadIdx.x;
  int lane = tid & 63, wave = tid >> 6;
  int wr = wave >> 1, wc = wave & 1;
  int g = lane >> 4, ln = lane & 15;
  const __hip_bfloat16* Ag = fmt + ((size_t)b * 1024 + bm * 128) * 512;
  const __hip_bfloat16* Bg = wall + (size_t)bn * 128 * 512;

  f32x4 acc[4][4] = {};
  uint4 ra[4], rb[4];
#pragma unroll
  for (int i = 0; i < 4; ++i) {
    int chunk = i * 256 + tid;
    int row = chunk >> 3, c16 = chunk & 7;
    ra[i] = *(const uint4*)(Ag + (size_t)row * 512 + c16 * 8);
    rb[i] = *(const uint4*)(Bg + (size_t)row * 512 + c16 * 8);
  }
  for (int kb = 0; kb < 8; ++kb) {
    __syncthreads();
#pragma unroll
    for (int i = 0; i < 4; ++i) {
      int chunk = i * 256 + tid;
      int row = chunk >> 3, c16 = chunk & 7;
      int off = row * 128 + ((c16 * 16) ^ ((row & 7) << 4));
      *(uint4*)(As + off) = ra[i];
      *(uint4*)(Bs + off) = rb[i];
    }
    __syncthreads();
    if (kb < 7) {
#pragma unroll
      for (int i = 0; i < 4; ++i) {
        int chunk = i * 256 + tid;
        int row = chunk >> 3, c16 = chunk & 7;
        ra[i] = *(const uint4*)(Ag + (size_t)row * 512 + (kb + 1) * 64 + c16 * 8);
        rb[i] = *(const uint4*)(Bg + (size_t)row * 512 + (kb + 1) * 64 + c16 * 8);
      }
    }
#pragma unroll
    for (int ks = 0; ks < 2; ++ks) {
      int kcol = ks * 64 + (g << 4);
      bf16x8 af[4], bfr[4];
#pragma unroll
      for (int m = 0; m < 4; ++m) {
        int row = wr * 64 + m * 16 + ln;
        af[m] = *(const bf16x8*)(As + row * 128 + (kcol ^ ((row & 7) << 4)));
      }
#pragma unroll
      for (int n = 0; n < 4; ++n) {
        int row = wc * 64 + n * 16 + ln;
        bfr[n] = *(const bf16x8*)(Bs + row * 128 + (kcol ^ ((row & 7) << 4)));
      }
#pragma unroll
      for (int m = 0; m < 4; ++m)
#pragma unroll
        for (int n = 0; n < 4; ++n)
          acc[m][n] = __builtin_amdgcn_mfma_f32_16x16x32_bf16(af[m], bfr[n], acc[m][n], 0, 0, 0);
    }
  }

  // ---- epilogue: restage C tile in LDS, then coalesced row stores ----
  __syncthreads();  // MFMA reads of As/Bs done before overwrite
  int otype = bn >> 2;  // 0=q, 1=k, 2=v
  int head = bn & 3;    // each 128-wide N tile is exactly one head
  if (otype != 2) {
    // stage [l][d] bf16, swizzled; scalar b16 writes
    float sc = (otype == 0) ? QSCALE : 1.0f;
#pragma unroll
    for (int m = 0; m < 4; ++m)
#pragma unroll
      for (int n = 0; n < 4; ++n) {
        int d = wc * 64 + n * 16 + ln;
#pragma unroll
        for (int r = 0; r < 4; ++r) {
          int l = wr * 64 + m * 16 + g * 4 + r;
          *(__hip_bfloat16*)(smem + l * 256 + ((d * 2) ^ ((l & 7) << 4))) =
              __float2bfloat16(acc[m][n][r] * sc);
        }
      }
    __syncthreads();
    __hip_bfloat16* dstb =
        (otype == 0 ? Qb : Kb) + (((size_t)(b * 4 + head) * 1024) + bm * 128) * 128;
#pragma unroll
    for (int i = 0; i < 8; ++i) {
      int idx = i * 256 + tid;
      int row = idx >> 4, c16 = idx & 15;
      uint4 v = *(const uint4*)(smem + row * 256 + ((c16 * 16) ^ ((row & 7) << 4)));
      *(uint4*)(dstb + (size_t)row * 128 + c16 * 8) = v;
    }
  } else {
    // stage transposed [d][l] bf16, swizzled; vector ushort4 writes (l-contiguous)
#pragma unroll
    for (int m = 0; m < 4; ++m)
#pragma unroll
      for (int n = 0; n < 4; ++n) {
        int d = wc * 64 + n * 16 + ln;
        int lbase = wr * 64 + m * 16 + g * 4;
        ushort4 pk;
        pk.x = bits_bf16(acc[m][n][0]);
        pk.y = bits_bf16(acc[m][n][1]);
        pk.z = bits_bf16(acc[m][n][2]);
        pk.w = bits_bf16(acc[m][n][3]);
        *(ushort4*)(smem + d * 256 + ((lbase * 2) ^ ((d & 7) << 4))) = pk;
      }
    __syncthreads();
    __hip_bfloat16* dstb = Vt + ((size_t)(b * 4 + head) * 128) * 1024 + bm * 128;
#pragma unroll
    for (int i = 0; i < 8; ++i) {
      int idx = i * 256 + tid;
      int row = idx >> 4, c16 = idx & 15;
      uint4 v = *(const uint4*)(smem + row * 256 + ((c16 * 16) ^ ((row & 7) << 4)));
      *(uint4*)(dstb + (size_t)row * 1024 + c16 * 8) = v;
    }
  }
}

// ---------------- kernel 4: bias tables via MFMA ----------------
// QRW/QRH[bh][l][m] = q[l] . rel[m]  (M=1024 l, N=64 m (63+pad0), K=128 d)
__global__ __launch_bounds__(256) void k_bias(const __hip_bfloat16* __restrict__ Qb,
                                              const __hip_bfloat16* __restrict__ relsb,
                                              float* __restrict__ QRW,
                                              float* __restrict__ QRH) {
  __shared__ char sh[32768];  // [2][64][128] bf16, swizzled
  int bx = blockIdx.x, bh = blockIdx.y;
  int tid = threadIdx.x, lane = tid & 63, wave = tid >> 6;
  int g = lane >> 4, ln = lane & 15;
#pragma unroll
  for (int i = 0; i < 8; ++i) {
    int chunk = i * 256 + tid;
    int row = chunk >> 4, c16 = chunk & 15;
    *(uint4*)(sh + row * 256 + ((c16 * 16) ^ ((row & 7) << 4))) =
        *(const uint4*)(relsb + (size_t)row * 128 + c16 * 8);
  }
  __syncthreads();
  size_t bhL = (size_t)bh * 1024;
  int l0 = bx * 128 + wave * 32;
  const __hip_bfloat16* Qg = Qb + (bhL + l0) * 128;
  bf16x8 a[2][4];
#pragma unroll
  for (int lf = 0; lf < 2; ++lf)
#pragma unroll
    for (int ks = 0; ks < 4; ++ks)
      a[lf][ks] = *(const bf16x8*)(Qg + (size_t)(lf * 16 + ln) * 128 + ks * 32 + g * 8);
#pragma unroll
  for (int t = 0; t < 2; ++t) {
    float* dst = (t == 0 ? QRW : QRH) + (bhL + l0) * 64;
#pragma unroll
    for (int n = 0; n < 4; ++n) {
      f32x4 acc2[2] = {};
#pragma unroll
      for (int ks = 0; ks < 4; ++ks) {
        int mrow = n * 16 + ln;
        bf16x8 bf = *(const bf16x8*)(sh + t * 16384 + mrow * 256 +
                                     ((ks * 64 + g * 16) ^ ((mrow & 7) << 4)));
#pragma unroll
        for (int lf = 0; lf < 2; ++lf)
          acc2[lf] = __builtin_amdgcn_mfma_f32_16x16x32_bf16(a[lf][ks], bf, acc2[lf], 0, 0, 0);
      }
#pragma unroll
      for (int lf = 0; lf < 2; ++lf)
#pragma unroll
        for (int r = 0; r < 4; ++r)
          dst[(size_t)(lf * 16 + g * 4 + r) * 64 + n * 16 + ln] = acc2[lf][r];
    }
  }
}

// ---------------- kernel 5: fused attention ----------------
__global__ __launch_bounds__(256) void k_attn(const __hip_bfloat16* __restrict__ Qb,
                                              const __hip_bfloat16* __restrict__ Kb,
                                              const __hip_bfloat16* __restrict__ Vt,
                                              const float* __restrict__ QRW,
                                              const float* __restrict__ QRH,
                                              float* __restrict__ out) {
  extern __shared__ char smem[];
  float* qrw_s = (float*)smem;               // [64][68] f32  17408 B
  float* qrh_s = (float*)(smem + 17408);     // [64][68] f32  17408 B
  char* kv = smem + 34816;                   // K tile [64][256B] (also Q stage) 16384 B
  char* vtl = smem + 51200;                  // V_t tile [128][128B] 16384 B
  char* pt = smem + 67584;                   // P [4 waves][16][128B] 8192 B
  float* rowstat = (float*)(smem + 75776);   // [4][16] f32

  int qt = blockIdx.x, bh = blockIdx.y;
  int b = bh >> 2, h = bh & 3;
  int tid = threadIdx.x, lane = tid & 63, wave = tid >> 6;
  int g = lane >> 4, ln = lane & 15;
  int q0 = qt * 64;
  size_t bhL = (size_t)bh * 1024;

  const __hip_bfloat16* Qg = Qb + (bhL + q0) * 128;
#pragma unroll
  for (int i = 0; i < 4; ++i) {
    int chunk = i * 256 + tid;
    int row = chunk >> 4, c16 = chunk & 15;
    *(uint4*)(kv + row * 256 + ((c16 * 16) ^ ((row & 7) << 4))) =
        *(const uint4*)(Qg + row * 128 + c16 * 8);
  }
#pragma unroll
  for (int i = 0; i < 4; ++i) {
    int chunk = i * 256 + tid;
    int row = chunk >> 4, c16 = chunk & 15;
    *(uint4*)(qrw_s + row * 68 + c16 * 4) =
        *(const uint4*)(QRW + (bhL + q0 + row) * 64 + c16 * 4);
    *(uint4*)(qrh_s + row * 68 + c16 * 4) =
        *(const uint4*)(QRH + (bhL + q0 + row) * 64 + c16 * 4);
  }
  __syncthreads();
  bf16x8 qa[4];
  int qrow = wave * 16 + ln;
#pragma unroll
  for (int ks = 0; ks < 4; ++ks)
    qa[ks] = *(const bf16x8*)(kv + qrow * 256 + ((ks * 64 + (g << 4)) ^ ((qrow & 7) << 4)));

  f32x4 acc_o[8] = {};
  float mrow[4] = {-1e30f, -1e30f, -1e30f, -1e30f};
  float lrow[4] = {0.f, 0.f, 0.f, 0.f};
  char* pw = pt + wave * 2048;

  for (int kt = 0; kt < 16; ++kt) {
    __syncthreads();
    const __hip_bfloat16* Kg = Kb + (bhL + kt * 64) * 128;
#pragma unroll
    for (int i = 0; i < 4; ++i) {
      int chunk = i * 256 + tid;
      int row = chunk >> 4, c16 = chunk & 15;
      *(uint4*)(kv + row * 256 + ((c16 * 16) ^ ((row & 7) << 4))) =
          *(const uint4*)(Kg + row * 128 + c16 * 8);
    }
    const __hip_bfloat16* Vg = Vt + (size_t)bh * 128 * 1024 + kt * 64;
#pragma unroll
    for (int i = 0; i < 4; ++i) {
      int chunk = i * 256 + tid;
      int row = chunk >> 3, c16 = chunk & 7;
      *(uint4*)(vtl + row * 128 + ((c16 * 16) ^ ((row & 7) << 4))) =
          *(const uint4*)(Vg + (size_t)row * 1024 + c16 * 8);
    }
    __syncthreads();

    f32x4 s[4] = {};
#pragma unroll
    for (int ks = 0; ks < 4; ++ks) {
      int kcol = ks * 64 + (g << 4);
#pragma unroll
      for (int n = 0; n < 4; ++n) {
        int krow = n * 16 + ln;
        bf16x8 kf = *(const bf16x8*)(kv + krow * 256 + (kcol ^ ((krow & 7) << 4)));
        s[n] = __builtin_amdgcn_mfma_f32_16x16x32_bf16(qa[ks], kf, s[n], 0, 0, 0);
      }
    }
#pragma unroll
    for (int n = 0; n < 4; ++n) {
      int key = kt * 64 + n * 16 + ln;
      int ry = key >> 5, cy = key & 31;
#pragma unroll
      for (int r = 0; r < 4; ++r) {
        int qloc = wave * 16 + g * 4 + r;
        int qg2 = q0 + qloc;
        s[n][r] += qrw_s[qloc * 68 + (cy - (qg2 & 31) + 31)] +
                   qrh_s[qloc * 68 + (ry - (qg2 >> 5) + 31)];
      }
    }
    float mt[4];
#pragma unroll
    for (int r = 0; r < 4; ++r)
      mt[r] = fmaxf(fmaxf(s[0][r], s[1][r]), fmaxf(s[2][r], s[3][r]));
#pragma unroll
    for (int off = 1; off < 16; off <<= 1)
#pragma unroll
      for (int r = 0; r < 4; ++r) mt[r] = fmaxf(mt[r], __shfl_xor(mt[r], off, 64));
    float alpha[4];
#pragma unroll
    for (int r = 0; r < 4; ++r) {
      float mn = fmaxf(mrow[r], mt[r]);
      alpha[r] = __expf(mrow[r] - mn);
      mrow[r] = mn;
    }
    float rs[4] = {0.f, 0.f, 0.f, 0.f};
#pragma unroll
    for (int n = 0; n < 4; ++n)
#pragma unroll
      for (int r = 0; r < 4; ++r) {
        s[n][r] = __expf(s[n][r] - mrow[r]);
        rs[r] += s[n][r];
      }
#pragma unroll
    for (int off = 1; off < 16; off <<= 1)
#pragma unroll
      for (int r = 0; r < 4; ++r) rs[r] += __shfl_xor(rs[r], off, 64);
#pragma unroll
    for (int r = 0; r < 4; ++r) lrow[r] = lrow[r] * alpha[r] + rs[r];
    if (ln == 0) {
#pragma unroll
      for (int r = 0; r < 4; ++r) rowstat[wave * 16 + g * 4 + r] = alpha[r];
    }
    float alpha_t = rowstat[wave * 16 + ln];
#pragma unroll
    for (int mf = 0; mf < 8; ++mf) acc_o[mf] *= alpha_t;
#pragma unroll
    for (int n = 0; n < 4; ++n)
#pragma unroll
      for (int r = 0; r < 4; ++r) {
        int prow = g * 4 + r;
        int pcb = (n * 16 + ln) * 2;
        *(__hip_bfloat16*)(pw + prow * 128 + (pcb ^ ((prow & 7) << 4))) =
            __float2bfloat16(s[n][r]);
      }
#pragma unroll
    for (int ks2 = 0; ks2 < 2; ++ks2) {
      int kcb = ks2 * 64 + (g << 4);
      bf16x8 pb = *(const bf16x8*)(pw + ln * 128 + (kcb ^ ((ln & 7) << 4)));
#pragma unroll
      for (int mf = 0; mf < 8; ++mf) {
        int vrow = mf * 16 + ln;
        bf16x8 av = *(const bf16x8*)(vtl + vrow * 128 + (kcb ^ ((vrow & 7) << 4)));
        acc_o[mf] = __builtin_amdgcn_mfma_f32_16x16x32_bf16(av, pb, acc_o[mf], 0, 0, 0);
      }
    }
  }
  if (ln == 0) {
#pragma unroll
    for (int r = 0; r < 4; ++r) rowstat[wave * 16 + g * 4 + r] = lrow[r];
  }
  float linv = 1.0f / rowstat[wave * 16 + ln];
  int qg2 = q0 + wave * 16 + ln;
#pragma unroll
  for (int mf = 0; mf < 8; ++mf) {
    int dbase = mf * 16 + g * 4;
#pragma unroll
    for (int r = 0; r < 4; ++r) {
      out[((size_t)(b * 512 + h * 128 + dbase + r)) * 1024 + qg2] = acc_o[mf][r] * linv;
    }
  }
}

extern "C" void kernel_launch(void* const* d_in, const int* in_sizes, int n_in,
                              void* d_out, int out_size, void* d_ws, size_t ws_size,
                              hipStream_t stream) {
  const float* fm = (const float*)d_in[0];
  const float* wqk = (const float*)d_in[1];
  const float* wv = (const float*)d_in[2];
  const float* relh = (const float*)d_in[3];
  const float* relw = (const float*)d_in[4];
  float* out = (float*)d_out;
  char* w = (char*)d_ws;

  __hip_bfloat16* fmt = (__hip_bfloat16*)w;                   // 16 MB  [B][L][C]
  __hip_bfloat16* wall = (__hip_bfloat16*)(w + 16777216);     // 1.5 MB [1536][512]
  __hip_bfloat16* Qb = (__hip_bfloat16*)(w + 18350080);       // 16 MB  [B][H][L][D] (scaled)
  __hip_bfloat16* Kb = (__hip_bfloat16*)(w + 35127296);       // 16 MB  [B][H][L][D]
  __hip_bfloat16* Vt = (__hip_bfloat16*)(w + 51904512);       // 16 MB  [B][H][D][L]
  float* QRW = (float*)(w + 68681728);                        // 16 MB  [B][H][L][64]
  float* QRH = (float*)(w + 85458944);                        // 16 MB  [B][H][L][64]
  __hip_bfloat16* relsb = (__hip_bfloat16*)(w + 102236160);   // 32 KB  [2][64][128]

  k_convw<<<3136, 256, 0, stream>>>(wqk, wv, relw, relh, wall, relsb);
  k_tfm<<<dim3(16, 8, 16), 256, 0, stream>>>(fm, fmt);
  k_gemm<<<dim3(8, 12, 16), 256, 0, stream>>>(fmt, wall, Qb, Kb, Vt);
  k_bias<<<dim3(8, 64), 256, 0, stream>>>(Qb, relsb, QRW, QRH);
  k_attn<<<dim3(16, 64), 256, 76032, stream>>>(Qb, Kb, Vt, QRW, QRH, out);
}

// Round 3
// 162.579 us; speedup vs baseline: 2.0485x; 1.4639x over previous
//
#include <hip/hip_runtime.h>
#include <hip/hip_bf16.h>
#include <math.h>

typedef __bf16 bf16x8 __attribute__((ext_vector_type(8)));
typedef float f32x4 __attribute__((ext_vector_type(4)));

#define QSCALE 0.08838834764831845f

static __device__ __forceinline__ unsigned short bits_bf16(float v) {
  __hip_bfloat16 h = __float2bfloat16(v);
  return *reinterpret_cast<unsigned short*>(&h);
}

// async global->LDS DMA, 16B per lane; LDS dest = wave-uniform base + lane*16
static __device__ __forceinline__ void gload16(const void* g, void* l) {
  __builtin_amdgcn_global_load_lds(
      (const __attribute__((address_space(1))) void*)g,
      (__attribute__((address_space(3))) void*)l, 16, 0, 0);
}

// ---------------- kernel 1: convert weights + rel tables to bf16 ----------------
__global__ __launch_bounds__(256) void k_convw(const float* __restrict__ wqk,
                                               const float* __restrict__ wv,
                                               const float* __restrict__ relw,
                                               const float* __restrict__ relh,
                                               __hip_bfloat16* __restrict__ wall,
                                               __hip_bfloat16* __restrict__ relsb) {
  int i = blockIdx.x * 256 + threadIdx.x;
  if (i < 1536 * 512) {
    float v = (i < 1024 * 512) ? wqk[i] : wv[i - 1024 * 512];
    wall[i] = __float2bfloat16(v);
  } else {
    int j = i - 1536 * 512;  // 0..16383 : [2][64][128], row 63 of each table = 0
    int t = j >> 13, m = (j >> 7) & 63, d = j & 127;
    float v = (m < 63) ? (t ? relh[m * 128 + d] : relw[m * 128 + d]) : 0.f;
    relsb[j] = __float2bfloat16(v);
  }
}

// ---------------- kernel 2: transpose + convert featuremap -> [B][L][C] bf16 ----------------
__global__ __launch_bounds__(256) void k_tfm(const float* __restrict__ fm,
                                             __hip_bfloat16* __restrict__ fmt) {
  __shared__ float t[64][65];
  int lt = blockIdx.x, ct = blockIdx.y, b = blockIdx.z;
  int tid = threadIdx.x;
  const float* src = fm + ((size_t)b * 512 + ct * 64) * 1024 + lt * 64;
#pragma unroll
  for (int i = 0; i < 16; ++i) {
    int idx = i * 256 + tid;
    int r = idx >> 6, cl = idx & 63;
    t[r][cl] = src[(size_t)r * 1024 + cl];
  }
  __syncthreads();
  __hip_bfloat16* dst = fmt + ((size_t)b * 1024 + lt * 64) * 512 + ct * 64;
#pragma unroll
  for (int i = 0; i < 16; ++i) {
    int idx = i * 256 + tid;
    int r = idx >> 6, cc = idx & 63;
    dst[(size_t)r * 512 + cc] = __float2bfloat16(t[cc][r]);
  }
}

// ---------------- kernel 3: QKV projection GEMM (m97 structure) ----------------
// C[l][o] = sum_c fmt[b][l][c] * wall[o][c];  M=1024(l), N=1536(o), K=512 per batch.
// global_load_lds w=16 staging; linear LDS + pre-swizzled source + XOR read.
__global__ __launch_bounds__(256) void k_gemm(const __hip_bfloat16* __restrict__ fmt,
                                              const __hip_bfloat16* __restrict__ wall,
                                              __hip_bfloat16* __restrict__ Qb,
                                              __hip_bfloat16* __restrict__ Kb,
                                              __hip_bfloat16* __restrict__ Vt) {
  __shared__ char smem[32768];
  char* As = smem;          // [128 rows][64 k] bf16 = 128B/row, content seg t = global seg t^(row&7)
  char* Bs = smem + 16384;
  int bm = blockIdx.x, bn = blockIdx.y, b = blockIdx.z;
  int tid = threadIdx.x;
  int lane = tid & 63, wave = tid >> 6;
  int wr = wave >> 1, wc = wave & 1;
  int g = lane >> 4, ln = lane & 15;
  const char* Ag = (const char*)(fmt + ((size_t)b * 1024 + bm * 128) * 512);
  const char* Bg = (const char*)(wall + (size_t)bn * 128 * 512);

  int j3 = lane >> 3, j7 = lane & 7;
  int segsrc = ((j7 ^ j3) << 4);  // pre-swizzled source seg (row&7 == j3)

  f32x4 acc[4][4] = {};
  for (int kb = 0; kb < 8; ++kb) {
#pragma unroll
    for (int i = 0; i < 4; ++i) {
      int R = (wave * 4 + i) * 8;  // 8 rows per 1KB DMA
      size_t go = (size_t)(R + j3) * 1024 + (size_t)kb * 128 + segsrc;
      gload16(Ag + go, As + R * 128);
      gload16(Bg + go, Bs + R * 128);
    }
    __syncthreads();  // drains vmcnt(0): staged data visible
#pragma unroll
    for (int ks = 0; ks < 2; ++ks) {
      int kcol = ks * 64 + (g << 4);
      bf16x8 af[4], bfr[4];
#pragma unroll
      for (int m = 0; m < 4; ++m) {
        int row = wr * 64 + m * 16 + ln;
        af[m] = *(const bf16x8*)(As + row * 128 + (kcol ^ ((ln & 7) << 4)));
      }
#pragma unroll
      for (int n = 0; n < 4; ++n) {
        int row = wc * 64 + n * 16 + ln;
        bfr[n] = *(const bf16x8*)(Bs + row * 128 + (kcol ^ ((ln & 7) << 4)));
      }
#pragma unroll
      for (int m = 0; m < 4; ++m)
#pragma unroll
        for (int n = 0; n < 4; ++n)
          acc[m][n] = __builtin_amdgcn_mfma_f32_16x16x32_bf16(af[m], bfr[n], acc[m][n], 0, 0, 0);
    }
    __syncthreads();  // reads done before next stage overwrites
  }

  // ---- epilogue: restage C tile in LDS, then coalesced row stores ----
  int otype = bn >> 2;  // 0=q, 1=k, 2=v
  int head = bn & 3;    // each 128-wide N tile is exactly one head
  if (otype != 2) {
    float sc = (otype == 0) ? QSCALE : 1.0f;
#pragma unroll
    for (int m = 0; m < 4; ++m)
#pragma unroll
      for (int n = 0; n < 4; ++n) {
        int d = wc * 64 + n * 16 + ln;
#pragma unroll
        for (int r = 0; r < 4; ++r) {
          int l = wr * 64 + m * 16 + g * 4 + r;
          *(__hip_bfloat16*)(smem + l * 256 + ((d * 2) ^ ((l & 7) << 4))) =
              __float2bfloat16(acc[m][n][r] * sc);
        }
      }
    __syncthreads();
    __hip_bfloat16* dstb =
        (otype == 0 ? Qb : Kb) + (((size_t)(b * 4 + head) * 1024) + bm * 128) * 128;
#pragma unroll
    for (int i = 0; i < 8; ++i) {
      int idx = i * 256 + tid;
      int row = idx >> 4, c16 = idx & 15;
      uint4 v = *(const uint4*)(smem + row * 256 + ((c16 * 16) ^ ((row & 7) << 4)));
      *(uint4*)(dstb + (size_t)row * 128 + c16 * 8) = v;
    }
  } else {
#pragma unroll
    for (int m = 0; m < 4; ++m)
#pragma unroll
      for (int n = 0; n < 4; ++n) {
        int d = wc * 64 + n * 16 + ln;
        int lbase = wr * 64 + m * 16 + g * 4;
        ushort4 pk;
        pk.x = bits_bf16(acc[m][n][0]);
        pk.y = bits_bf16(acc[m][n][1]);
        pk.z = bits_bf16(acc[m][n][2]);
        pk.w = bits_bf16(acc[m][n][3]);
        *(ushort4*)(smem + d * 256 + ((lbase * 2) ^ ((d & 7) << 4))) = pk;
      }
    __syncthreads();
    __hip_bfloat16* dstb = Vt + ((size_t)(b * 4 + head) * 128) * 1024 + bm * 128;
#pragma unroll
    for (int i = 0; i < 8; ++i) {
      int idx = i * 256 + tid;
      int row = idx >> 4, c16 = idx & 15;
      uint4 v = *(const uint4*)(smem + row * 256 + ((c16 * 16) ^ ((row & 7) << 4)));
      *(uint4*)(dstb + (size_t)row * 1024 + c16 * 8) = v;
    }
  }
}

// ---------------- kernel 4: bias tables via MFMA ----------------
__global__ __launch_bounds__(256) void k_bias(const __hip_bfloat16* __restrict__ Qb,
                                              const __hip_bfloat16* __restrict__ relsb,
                                              float* __restrict__ QRW,
                                              float* __restrict__ QRH) {
  __shared__ char sh[32768];  // [2][64][128] bf16, swizzled
  int bx = blockIdx.x, bh = blockIdx.y;
  int tid = threadIdx.x, lane = tid & 63, wave = tid >> 6;
  int g = lane >> 4, ln = lane & 15;
#pragma unroll
  for (int i = 0; i < 8; ++i) {
    int chunk = i * 256 + tid;
    int row = chunk >> 4, c16 = chunk & 15;
    *(uint4*)(sh + row * 256 + ((c16 * 16) ^ ((row & 7) << 4))) =
        *(const uint4*)(relsb + (size_t)row * 128 + c16 * 8);
  }
  __syncthreads();
  size_t bhL = (size_t)bh * 1024;
  int l0 = bx * 128 + wave * 32;
  const __hip_bfloat16* Qg = Qb + (bhL + l0) * 128;
  bf16x8 a[2][4];
#pragma unroll
  for (int lf = 0; lf < 2; ++lf)
#pragma unroll
    for (int ks = 0; ks < 4; ++ks)
      a[lf][ks] = *(const bf16x8*)(Qg + (size_t)(lf * 16 + ln) * 128 + ks * 32 + g * 8);
#pragma unroll
  for (int t = 0; t < 2; ++t) {
    float* dst = (t == 0 ? QRW : QRH) + (bhL + l0) * 64;
#pragma unroll
    for (int n = 0; n < 4; ++n) {
      f32x4 acc2[2] = {};
#pragma unroll
      for (int ks = 0; ks < 4; ++ks) {
        int mrow = n * 16 + ln;
        bf16x8 bf = *(const bf16x8*)(sh + t * 16384 + mrow * 256 +
                                     ((ks * 64 + g * 16) ^ ((mrow & 7) << 4)));
#pragma unroll
        for (int lf = 0; lf < 2; ++lf)
          acc2[lf] = __builtin_amdgcn_mfma_f32_16x16x32_bf16(a[lf][ks], bf, acc2[lf], 0, 0, 0);
      }
#pragma unroll
      for (int lf = 0; lf < 2; ++lf)
#pragma unroll
        for (int r = 0; r < 4; ++r)
          dst[(size_t)(lf * 16 + g * 4 + r) * 64 + n * 16 + ln] = acc2[lf][r];
    }
  }
}

// ---------------- kernel 5: fused attention ----------------
__global__ __launch_bounds__(256) void k_attn(const __hip_bfloat16* __restrict__ Qb,
                                              const __hip_bfloat16* __restrict__ Kb,
                                              const __hip_bfloat16* __restrict__ Vt,
                                              const float* __restrict__ QRW,
                                              const float* __restrict__ QRH,
                                              float* __restrict__ out) {
  extern __shared__ char smem[];
  float* qrw_s = (float*)smem;               // [64][68] f32  17408 B
  float* qrh_s = (float*)(smem + 17408);     // [64][68] f32  17408 B
  char* kv = smem + 34816;                   // K tile [64][256B] (also Q stage) 16384 B
  char* vtl = smem + 51200;                  // V_t tile [128][128B] 16384 B
  char* pt = smem + 67584;                   // P [4 waves][16][128B] 8192 B
  float* rowstat = (float*)(smem + 75776);   // [4][16] f32

  int qt = blockIdx.x, bh = blockIdx.y;
  int b = bh >> 2, h = bh & 3;
  int tid = threadIdx.x, lane = tid & 63, wave = tid >> 6;
  int g = lane >> 4, ln = lane & 15;
  int q0 = qt * 64;
  size_t bhL = (size_t)bh * 1024;

  // ---- gload_lds staging helpers (pre-swizzled source, LDS linear) ----
  // Q/K tile: 64 rows x 256B; instr covers 4 rows; row&7 = (i&1)*4 + (lane>>4)
  const char* Qg = (const char*)(Qb + (bhL + q0) * 128);
#pragma unroll
  for (int i = 0; i < 4; ++i) {
    int R = (wave * 4 + i) * 4;
    int seg = ((lane & 15) ^ (((i & 1) * 4) + (lane >> 4))) << 4;
    gload16(Qg + (size_t)(R + (lane >> 4)) * 256 + seg, kv + R * 256);
  }
#pragma unroll
  for (int i = 0; i < 4; ++i) {
    int chunk = i * 256 + tid;
    int row = chunk >> 4, c16 = chunk & 15;
    *(uint4*)(qrw_s + row * 68 + c16 * 4) =
        *(const uint4*)(QRW + (bhL + q0 + row) * 64 + c16 * 4);
    *(uint4*)(qrh_s + row * 68 + c16 * 4) =
        *(const uint4*)(QRH + (bhL + q0 + row) * 64 + c16 * 4);
  }
  __syncthreads();
  bf16x8 qa[4];
  int qrow = wave * 16 + ln;
#pragma unroll
  for (int ks = 0; ks < 4; ++ks)
    qa[ks] = *(const bf16x8*)(kv + qrow * 256 + ((ks * 64 + (g << 4)) ^ ((qrow & 7) << 4)));

  f32x4 acc_o[8] = {};
  float mrow[4] = {-1e30f, -1e30f, -1e30f, -1e30f};
  float lrow[4] = {0.f, 0.f, 0.f, 0.f};
  char* pw = pt + wave * 2048;
  const char* Kg0 = (const char*)(Kb + bhL * 128);
  const char* Vg0 = (const char*)(Vt + (size_t)bh * 128 * 1024);
  int j3 = lane >> 3, j7 = lane & 7;
  int segv = ((j7 ^ j3) << 4);

  for (int kt = 0; kt < 16; ++kt) {
    __syncthreads();  // prior reads of kv/vtl done (drains lgkm too)
    const char* Kg = Kg0 + (size_t)kt * 64 * 256;
#pragma unroll
    for (int i = 0; i < 4; ++i) {
      int R = (wave * 4 + i) * 4;
      int seg = ((lane & 15) ^ (((i & 1) * 4) + (lane >> 4))) << 4;
      gload16(Kg + (size_t)(R + (lane >> 4)) * 256 + seg, kv + R * 256);
    }
    const char* Vg = Vg0 + (size_t)kt * 128;  // row d stride 2048B, 128B used per row
#pragma unroll
    for (int i = 0; i < 4; ++i) {
      int R = (wave * 4 + i) * 8;
      gload16(Vg + (size_t)(R + j3) * 2048 + segv, vtl + R * 128);
    }
    __syncthreads();

    f32x4 s[4] = {};
#pragma unroll
    for (int ks = 0; ks < 4; ++ks) {
      int kcol = ks * 64 + (g << 4);
#pragma unroll
      for (int n = 0; n < 4; ++n) {
        int krow = n * 16 + ln;
        bf16x8 kf = *(const bf16x8*)(kv + krow * 256 + (kcol ^ ((krow & 7) << 4)));
        s[n] = __builtin_amdgcn_mfma_f32_16x16x32_bf16(qa[ks], kf, s[n], 0, 0, 0);
      }
    }
#pragma unroll
    for (int n = 0; n < 4; ++n) {
      int key = kt * 64 + n * 16 + ln;
      int ry = key >> 5, cy = key & 31;
#pragma unroll
      for (int r = 0; r < 4; ++r) {
        int qloc = wave * 16 + g * 4 + r;
        int qg2 = q0 + qloc;
        s[n][r] += qrw_s[qloc * 68 + (cy - (qg2 & 31) + 31)] +
                   qrh_s[qloc * 68 + (ry - (qg2 >> 5) + 31)];
      }
    }
    float mt[4];
#pragma unroll
    for (int r = 0; r < 4; ++r)
      mt[r] = fmaxf(fmaxf(s[0][r], s[1][r]), fmaxf(s[2][r], s[3][r]));
#pragma unroll
    for (int off = 1; off < 16; off <<= 1)
#pragma unroll
      for (int r = 0; r < 4; ++r) mt[r] = fmaxf(mt[r], __shfl_xor(mt[r], off, 64));
    float alpha[4];
#pragma unroll
    for (int r = 0; r < 4; ++r) {
      float mn = fmaxf(mrow[r], mt[r]);
      alpha[r] = __expf(mrow[r] - mn);
      mrow[r] = mn;
    }
    float rs[4] = {0.f, 0.f, 0.f, 0.f};
#pragma unroll
    for (int n = 0; n < 4; ++n)
#pragma unroll
      for (int r = 0; r < 4; ++r) {
        s[n][r] = __expf(s[n][r] - mrow[r]);
        rs[r] += s[n][r];
      }
#pragma unroll
    for (int off = 1; off < 16; off <<= 1)
#pragma unroll
      for (int r = 0; r < 4; ++r) rs[r] += __shfl_xor(rs[r], off, 64);
#pragma unroll
    for (int r = 0; r < 4; ++r) lrow[r] = lrow[r] * alpha[r] + rs[r];
    if (ln == 0) {
#pragma unroll
      for (int r = 0; r < 4; ++r) rowstat[wave * 16 + g * 4 + r] = alpha[r];
    }
    float alpha_t = rowstat[wave * 16 + ln];
#pragma unroll
    for (int mf = 0; mf < 8; ++mf) acc_o[mf] *= alpha_t;
#pragma unroll
    for (int n = 0; n < 4; ++n)
#pragma unroll
      for (int r = 0; r < 4; ++r) {
        int prow = g * 4 + r;
        int pcb = (n * 16 + ln) * 2;
        *(__hip_bfloat16*)(pw + prow * 128 + (pcb ^ ((prow & 7) << 4))) =
            __float2bfloat16(s[n][r]);
      }
#pragma unroll
    for (int ks2 = 0; ks2 < 2; ++ks2) {
      int kcb = ks2 * 64 + (g << 4);
      bf16x8 pb = *(const bf16x8*)(pw + ln * 128 + (kcb ^ ((ln & 7) << 4)));
#pragma unroll
      for (int mf = 0; mf < 8; ++mf) {
        int vrow = mf * 16 + ln;
        bf16x8 av = *(const bf16x8*)(vtl + vrow * 128 + (kcb ^ ((vrow & 7) << 4)));
        acc_o[mf] = __builtin_amdgcn_mfma_f32_16x16x32_bf16(av, pb, acc_o[mf], 0, 0, 0);
      }
    }
  }
  if (ln == 0) {
#pragma unroll
    for (int r = 0; r < 4; ++r) rowstat[wave * 16 + g * 4 + r] = lrow[r];
  }
  float linv = 1.0f / rowstat[wave * 16 + ln];
  int qg2 = q0 + wave * 16 + ln;
#pragma unroll
  for (int mf = 0; mf < 8; ++mf) {
    int dbase = mf * 16 + g * 4;
#pragma unroll
    for (int r = 0; r < 4; ++r) {
      out[((size_t)(b * 512 + h * 128 + dbase + r)) * 1024 + qg2] = acc_o[mf][r] * linv;
    }
  }
}

extern "C" void kernel_launch(void* const* d_in, const int* in_sizes, int n_in,
                              void* d_out, int out_size, void* d_ws, size_t ws_size,
                              hipStream_t stream) {
  const float* fm = (const float*)d_in[0];
  const float* wqk = (const float*)d_in[1];
  const float* wv = (const float*)d_in[2];
  const float* relh = (const float*)d_in[3];
  const float* relw = (const float*)d_in[4];
  float* out = (float*)d_out;
  char* w = (char*)d_ws;

  __hip_bfloat16* fmt = (__hip_bfloat16*)w;                   // 16 MB  [B][L][C]
  __hip_bfloat16* wall = (__hip_bfloat16*)(w + 16777216);     // 1.5 MB [1536][512]
  __hip_bfloat16* Qb = (__hip_bfloat16*)(w + 18350080);       // 16 MB  [B][H][L][D] (scaled)
  __hip_bfloat16* Kb = (__hip_bfloat16*)(w + 35127296);       // 16 MB  [B][H][L][D]
  __hip_bfloat16* Vt = (__hip_bfloat16*)(w + 51904512);       // 16 MB  [B][H][D][L]
  float* QRW = (float*)(w + 68681728);                        // 16 MB  [B][H][L][64]
  float* QRH = (float*)(w + 85458944);                        // 16 MB  [B][H][L][64]
  __hip_bfloat16* relsb = (__hip_bfloat16*)(w + 102236160);   // 32 KB  [2][64][128]

  k_convw<<<3136, 256, 0, stream>>>(wqk, wv, relw, relh, wall, relsb);
  k_tfm<<<dim3(16, 8, 16), 256, 0, stream>>>(fm, fmt);
  k_gemm<<<dim3(8, 12, 16), 256, 0, stream>>>(fmt, wall, Qb, Kb, Vt);
  k_bias<<<dim3(8, 64), 256, 0, stream>>>(Qb, relsb, QRW, QRH);
  k_attn<<<dim3(16, 64), 256, 76032, stream>>>(Qb, Kb, Vt, QRW, QRH, out);
}

// Round 7
// 158.667 us; speedup vs baseline: 2.0990x; 1.0247x over previous
//
#include <hip/hip_runtime.h>
#include <hip/hip_bf16.h>
#include <math.h>

typedef __bf16 bf16x8 __attribute__((ext_vector_type(8)));
typedef float f32x4 __attribute__((ext_vector_type(4)));

// QSCALE * log2(e): Q (and the bias tables derived from Q) live in the exp2
// domain, so softmax needs only exp2f.
#define QSCALE_L2E (0.08838834764831845f * 1.4426950408889634f)

static __device__ __forceinline__ unsigned short bits_bf16(float v) {
  __hip_bfloat16 h = __float2bfloat16(v);
  return *reinterpret_cast<unsigned short*>(&h);
}

// async global->LDS DMA, 16B per lane; LDS dest = wave-uniform base + lane*16
static __device__ __forceinline__ void gload16(const void* g, void* l) {
  __builtin_amdgcn_global_load_lds(
      (const __attribute__((address_space(1))) void*)g,
      (__attribute__((address_space(3))) void*)l, 16, 0, 0);
}

// ---------------- kernel 1: convert weights + rel tables to bf16 ----------------
__global__ __launch_bounds__(256) void k_convw(const float* __restrict__ wqk,
                                               const float* __restrict__ wv,
                                               const float* __restrict__ relw,
                                               const float* __restrict__ relh,
                                               __hip_bfloat16* __restrict__ wall,
                                               __hip_bfloat16* __restrict__ relsb) {
  int i = blockIdx.x * 256 + threadIdx.x;
  if (i < 1536 * 512) {
    float v = (i < 1024 * 512) ? wqk[i] : wv[i - 1024 * 512];
    wall[i] = __float2bfloat16(v);
  } else {
    int j = i - 1536 * 512;  // 0..16383 : [2][64][128], row 63 of each table = 0
    int t = j >> 13, m = (j >> 7) & 63, d = j & 127;
    float v = (m < 63) ? (t ? relh[m * 128 + d] : relw[m * 128 + d]) : 0.f;
    relsb[j] = __float2bfloat16(v);
  }
}

// ---------------- kernel 2: transpose + convert featuremap -> [B][L][C] bf16 ----------------
__global__ __launch_bounds__(256) void k_tfm(const float* __restrict__ fm,
                                             __hip_bfloat16* __restrict__ fmt) {
  __shared__ float t[64][65];
  int lt = blockIdx.x, ct = blockIdx.y, b = blockIdx.z;
  int tid = threadIdx.x;
  const float* src = fm + ((size_t)b * 512 + ct * 64) * 1024 + lt * 64;
#pragma unroll
  for (int i = 0; i < 16; ++i) {
    int idx = i * 256 + tid;
    int r = idx >> 6, cl = idx & 63;
    t[r][cl] = src[(size_t)r * 1024 + cl];
  }
  __syncthreads();
  __hip_bfloat16* dst = fmt + ((size_t)b * 1024 + lt * 64) * 512 + ct * 64;
#pragma unroll
  for (int i = 0; i < 16; ++i) {
    int idx = i * 256 + tid;
    int r = idx >> 6, cc = idx & 63;
    dst[(size_t)r * 512 + cc] = __float2bfloat16(t[cc][r]);
  }
}

// ---------------- kernel 3: QKV projection GEMM (m97 structure) ----------------
__global__ __launch_bounds__(256) void k_gemm(const __hip_bfloat16* __restrict__ fmt,
                                              const __hip_bfloat16* __restrict__ wall,
                                              __hip_bfloat16* __restrict__ Qb,
                                              __hip_bfloat16* __restrict__ Kb,
                                              __hip_bfloat16* __restrict__ Vt) {
  __shared__ char smem[32768];
  char* As = smem;
  char* Bs = smem + 16384;
  int bm = blockIdx.x, bn = blockIdx.y, b = blockIdx.z;
  int tid = threadIdx.x;
  int lane = tid & 63, wave = tid >> 6;
  int wr = wave >> 1, wc = wave & 1;
  int g = lane >> 4, ln = lane & 15;
  const char* Ag = (const char*)(fmt + ((size_t)b * 1024 + bm * 128) * 512);
  const char* Bg = (const char*)(wall + (size_t)bn * 128 * 512);

  int j3 = lane >> 3, j7 = lane & 7;
  int segsrc = ((j7 ^ j3) << 4);  // pre-swizzled source seg (row&7 == j3)

  f32x4 acc[4][4] = {};
  for (int kb = 0; kb < 8; ++kb) {
#pragma unroll
    for (int i = 0; i < 4; ++i) {
      int R = (wave * 4 + i) * 8;  // 8 rows per 1KB DMA
      size_t go = (size_t)(R + j3) * 1024 + (size_t)kb * 128 + segsrc;
      gload16(Ag + go, As + R * 128);
      gload16(Bg + go, Bs + R * 128);
    }
    __syncthreads();
#pragma unroll
    for (int ks = 0; ks < 2; ++ks) {
      int kcol = ks * 64 + (g << 4);
      bf16x8 af[4], bfr[4];
#pragma unroll
      for (int m = 0; m < 4; ++m) {
        int row = wr * 64 + m * 16 + ln;
        af[m] = *(const bf16x8*)(As + row * 128 + (kcol ^ ((ln & 7) << 4)));
      }
#pragma unroll
      for (int n = 0; n < 4; ++n) {
        int row = wc * 64 + n * 16 + ln;
        bfr[n] = *(const bf16x8*)(Bs + row * 128 + (kcol ^ ((ln & 7) << 4)));
      }
#pragma unroll
      for (int m = 0; m < 4; ++m)
#pragma unroll
        for (int n = 0; n < 4; ++n)
          acc[m][n] = __builtin_amdgcn_mfma_f32_16x16x32_bf16(af[m], bfr[n], acc[m][n], 0, 0, 0);
    }
    __syncthreads();
  }

  // ---- epilogue: restage C tile in LDS, then coalesced row stores ----
  int otype = bn >> 2;  // 0=q, 1=k, 2=v
  int head = bn & 3;
  if (otype != 2) {
    float sc = (otype == 0) ? QSCALE_L2E : 1.0f;
#pragma unroll
    for (int m = 0; m < 4; ++m)
#pragma unroll
      for (int n = 0; n < 4; ++n) {
        int d = wc * 64 + n * 16 + ln;
#pragma unroll
        for (int r = 0; r < 4; ++r) {
          int l = wr * 64 + m * 16 + g * 4 + r;
          *(__hip_bfloat16*)(smem + l * 256 + ((d * 2) ^ ((l & 7) << 4))) =
              __float2bfloat16(acc[m][n][r] * sc);
        }
      }
    __syncthreads();
    __hip_bfloat16* dstb =
        (otype == 0 ? Qb : Kb) + (((size_t)(b * 4 + head) * 1024) + bm * 128) * 128;
#pragma unroll
    for (int i = 0; i < 8; ++i) {
      int idx = i * 256 + tid;
      int row = idx >> 4, c16 = idx & 15;
      uint4 v = *(const uint4*)(smem + row * 256 + ((c16 * 16) ^ ((row & 7) << 4)));
      *(uint4*)(dstb + (size_t)row * 128 + c16 * 8) = v;
    }
  } else {
#pragma unroll
    for (int m = 0; m < 4; ++m)
#pragma unroll
      for (int n = 0; n < 4; ++n) {
        int d = wc * 64 + n * 16 + ln;
        int lbase = wr * 64 + m * 16 + g * 4;
        ushort4 pk;
        pk.x = bits_bf16(acc[m][n][0]);
        pk.y = bits_bf16(acc[m][n][1]);
        pk.z = bits_bf16(acc[m][n][2]);
        pk.w = bits_bf16(acc[m][n][3]);
        *(ushort4*)(smem + d * 256 + ((lbase * 2) ^ ((d & 7) << 4))) = pk;
      }
    __syncthreads();
    __hip_bfloat16* dstb = Vt + ((size_t)(b * 4 + head) * 128) * 1024 + bm * 128;
#pragma unroll
    for (int i = 0; i < 8; ++i) {
      int idx = i * 256 + tid;
      int row = idx >> 4, c16 = idx & 15;
      uint4 v = *(const uint4*)(smem + row * 256 + ((c16 * 16) ^ ((row & 7) << 4)));
      *(uint4*)(dstb + (size_t)row * 1024 + c16 * 8) = v;
    }
  }
}

// ---------------- kernel 4: bias tables via MFMA ----------------
// Tables inherit the log2e factor from Qb automatically.
__global__ __launch_bounds__(256) void k_bias(const __hip_bfloat16* __restrict__ Qb,
                                              const __hip_bfloat16* __restrict__ relsb,
                                              float* __restrict__ QRW,
                                              float* __restrict__ QRH) {
  __shared__ char sh[32768];  // [2][64][128] bf16, swizzled
  int bx = blockIdx.x, bh = blockIdx.y;
  int tid = threadIdx.x, lane = tid & 63, wave = tid >> 6;
  int g = lane >> 4, ln = lane & 15;
#pragma unroll
  for (int i = 0; i < 8; ++i) {
    int chunk = i * 256 + tid;
    int row = chunk >> 4, c16 = chunk & 15;
    *(uint4*)(sh + row * 256 + ((c16 * 16) ^ ((row & 7) << 4))) =
        *(const uint4*)(relsb + (size_t)row * 128 + c16 * 8);
  }
  __syncthreads();
  size_t bhL = (size_t)bh * 1024;
  int l0 = bx * 128 + wave * 32;
  const __hip_bfloat16* Qg = Qb + (bhL + l0) * 128;
  bf16x8 a[2][4];
#pragma unroll
  for (int lf = 0; lf < 2; ++lf)
#pragma unroll
    for (int ks = 0; ks < 4; ++ks)
      a[lf][ks] = *(const bf16x8*)(Qg + (size_t)(lf * 16 + ln) * 128 + ks * 32 + g * 8);
#pragma unroll
  for (int t = 0; t < 2; ++t) {
    float* dst = (t == 0 ? QRW : QRH) + (bhL + l0) * 64;
#pragma unroll
    for (int n = 0; n < 4; ++n) {
      f32x4 acc2[2] = {};
#pragma unroll
      for (int ks = 0; ks < 4; ++ks) {
        int mrow = n * 16 + ln;
        bf16x8 bf = *(const bf16x8*)(sh + t * 16384 + mrow * 256 +
                                     ((ks * 64 + g * 16) ^ ((mrow & 7) << 4)));
#pragma unroll
        for (int lf = 0; lf < 2; ++lf)
          acc2[lf] = __builtin_amdgcn_mfma_f32_16x16x32_bf16(a[lf][ks], bf, acc2[lf], 0, 0, 0);
      }
#pragma unroll
      for (int lf = 0; lf < 2; ++lf)
#pragma unroll
        for (int r = 0; r < 4; ++r)
          dst[(size_t)(lf * 16 + g * 4 + r) * 64 + n * 16 + ln] = acc2[lf][r];
    }
  }
}

// ---------------- kernel 5: fused attention ----------------
// Online-softmax (verified structure) in the exp2 domain; bias from registers
// (wb kt-invariant, hb 2 broadcasts/kt); l = sum P from ones-row MFMA (row 128
// of V_t), rescaled by alpha like every other accumulator row.
__global__ __launch_bounds__(256) void k_attn(const __hip_bfloat16* __restrict__ Qb,
                                              const __hip_bfloat16* __restrict__ Kb,
                                              const __hip_bfloat16* __restrict__ Vt,
                                              const float* __restrict__ QRW,
                                              const float* __restrict__ QRH,
                                              float* __restrict__ out) {
  extern __shared__ char smem[];
  float* qrw_s = (float*)smem;               // [64][68] f32  17408 B
  float* qrh_s = (float*)(smem + 17408);     // [64][68] f32  17408 B
  char* kv = smem + 34816;                   // K tile [64][256B] (also Q stage) 16384 B
  char* vtl = smem + 51200;                  // V_t tile [144][128B] 18432 B (rows 128..143: ones/zeros)
  char* pt = smem + 69632;                   // P [4 waves][16][128B] 8192 B
  float* rowstat = (float*)(smem + 77824);   // [4][16] f32

  int qt = blockIdx.x, bh = blockIdx.y;
  int b = bh >> 2, h = bh & 3;
  int tid = threadIdx.x, lane = tid & 63, wave = tid >> 6;
  int g = lane >> 4, ln = lane & 15;
  int q0 = qt * 64;
  size_t bhL = (size_t)bh * 1024;

  // stage Q tile via gload_lds (pre-swizzled source, LDS linear)
  const char* Qg = (const char*)(Qb + (bhL + q0) * 128);
#pragma unroll
  for (int i = 0; i < 4; ++i) {
    int R = (wave * 4 + i) * 4;
    int seg = ((lane & 15) ^ (((i & 1) * 4) + (lane >> 4))) << 4;
    gload16(Qg + (size_t)(R + (lane >> 4)) * 256 + seg, kv + R * 256);
  }
  // stage bias tables [64 q][64 m], stride 68
#pragma unroll
  for (int i = 0; i < 4; ++i) {
    int chunk = i * 256 + tid;
    int row = chunk >> 4, c16 = chunk & 15;
    *(uint4*)(qrw_s + row * 68 + c16 * 4) =
        *(const uint4*)(QRW + (bhL + q0 + row) * 64 + c16 * 4);
    *(uint4*)(qrh_s + row * 68 + c16 * 4) =
        *(const uint4*)(QRH + (bhL + q0 + row) * 64 + c16 * 4);
  }
  // ones/zeros rows 128..143 of vtl (row 128 = bf16 1.0; swizzle identity there)
#pragma unroll
  for (int i = 0; i < 2; ++i) {
    int idx = i * 256 + tid;  // 512 dwords = 16 rows x 128B
    ((unsigned*)(vtl + 128 * 128))[idx] = (idx < 32) ? 0x3F803F80u : 0u;
  }
  __syncthreads();

  bf16x8 qa[4];
  int qrow = wave * 16 + ln;
#pragma unroll
  for (int ks = 0; ks < 4; ++ks)
    qa[ks] = *(const bf16x8*)(kv + qrow * 256 + ((ks * 64 + (g << 4)) ^ ((qrow & 7) << 4)));

  // per-lane bias decomposition: w-part kt-invariant, h-part 2 broadcasts/kt
  float wb[2][4];
  const float* hptr[4];
#pragma unroll
  for (int r = 0; r < 4; ++r) {
    int qloc = wave * 16 + g * 4 + r;
    int qg2 = q0 + qloc;
    int cx = qg2 & 31, rx = qg2 >> 5;
    wb[0][r] = qrw_s[qloc * 68 + (ln - cx + 31)];
    wb[1][r] = qrw_s[qloc * 68 + (ln - cx + 47)];
    hptr[r] = qrh_s + qloc * 68 + (31 - rx);
  }

  f32x4 acc_o[9] = {};
  float mrow[4] = {-1e30f, -1e30f, -1e30f, -1e30f};
  char* pw = pt + wave * 2048;
  const char* Kg0 = (const char*)(Kb + bhL * 128);
  const char* Vg0 = (const char*)(Vt + (size_t)bh * 128 * 1024);
  int j3 = lane >> 3, j7 = lane & 7;
  int segv = ((j7 ^ j3) << 4);

  for (int kt = 0; kt < 16; ++kt) {
    __syncthreads();  // prior reads of kv/vtl done
    const char* Kg = Kg0 + (size_t)kt * 64 * 256;
#pragma unroll
    for (int i = 0; i < 4; ++i) {
      int R = (wave * 4 + i) * 4;
      int seg = ((lane & 15) ^ (((i & 1) * 4) + (lane >> 4))) << 4;
      gload16(Kg + (size_t)(R + (lane >> 4)) * 256 + seg, kv + R * 256);
    }
    const char* Vg = Vg0 + (size_t)kt * 128;
#pragma unroll
    for (int i = 0; i < 4; ++i) {
      int R = (wave * 4 + i) * 8;
      gload16(Vg + (size_t)(R + j3) * 2048 + segv, vtl + R * 128);
    }
    __syncthreads();

    // S = Q K^T  (log2 domain)
    f32x4 s[4] = {};
#pragma unroll
    for (int ks = 0; ks < 4; ++ks) {
      int kcol = ks * 64 + (g << 4);
#pragma unroll
      for (int n = 0; n < 4; ++n) {
        int krow = n * 16 + ln;
        bf16x8 kf = *(const bf16x8*)(kv + krow * 256 + (kcol ^ ((krow & 7) << 4)));
        s[n] = __builtin_amdgcn_mfma_f32_16x16x32_bf16(qa[ks], kf, s[n], 0, 0, 0);
      }
    }
    // + bias from registers: cy=(n&1)*16+ln (kt-invariant), ry=2kt+(n>>1)
    float hb0[4], hb1[4];
#pragma unroll
    for (int r = 0; r < 4; ++r) {
      hb0[r] = hptr[r][kt * 2];
      hb1[r] = hptr[r][kt * 2 + 1];
    }
#pragma unroll
    for (int n = 0; n < 4; ++n)
#pragma unroll
      for (int r = 0; r < 4; ++r)
        s[n][r] += wb[n & 1][r] + ((n >> 1) ? hb1[r] : hb0[r]);
    // online max (verified structure), exp2 domain
    float mt[4];
#pragma unroll
    for (int r = 0; r < 4; ++r)
      mt[r] = fmaxf(fmaxf(s[0][r], s[1][r]), fmaxf(s[2][r], s[3][r]));
#pragma unroll
    for (int off = 1; off < 16; off <<= 1)
#pragma unroll
      for (int r = 0; r < 4; ++r) mt[r] = fmaxf(mt[r], __shfl_xor(mt[r], off, 64));
    float alpha[4];
#pragma unroll
    for (int r = 0; r < 4; ++r) {
      float mn = fmaxf(mrow[r], mt[r]);
      alpha[r] = exp2f(mrow[r] - mn);
      mrow[r] = mn;
    }
#pragma unroll
    for (int n = 0; n < 4; ++n)
#pragma unroll
      for (int r = 0; r < 4; ++r) s[n][r] = exp2f(s[n][r] - mrow[r]);
    // broadcast alpha transposed (per-wave LDS, same-wave DS ordering)
    if (ln == 0) {
#pragma unroll
      for (int r = 0; r < 4; ++r) rowstat[wave * 16 + g * 4 + r] = alpha[r];
    }
    float alpha_t = rowstat[wave * 16 + ln];
#pragma unroll
    for (int mf = 0; mf < 9; ++mf) acc_o[mf] *= alpha_t;
    // write P (bf16, swizzled, per-wave region)
#pragma unroll
    for (int n = 0; n < 4; ++n)
#pragma unroll
      for (int r = 0; r < 4; ++r) {
        int prow = g * 4 + r;
        int pcb = (n * 16 + ln) * 2;
        *(__hip_bfloat16*)(pw + prow * 128 + (pcb ^ ((prow & 7) << 4))) =
            __float2bfloat16(s[n][r]);
      }
    // PV (transposed): acc_o[d][q] += V_t . P^T ; mf=8 accumulates l = sum P
#pragma unroll
    for (int ks2 = 0; ks2 < 2; ++ks2) {
      int kcb = ks2 * 64 + (g << 4);
      bf16x8 pb = *(const bf16x8*)(pw + ln * 128 + (kcb ^ ((ln & 7) << 4)));
#pragma unroll
      for (int mf = 0; mf < 9; ++mf) {
        int vrow = mf * 16 + ln;
        bf16x8 av = *(const bf16x8*)(vtl + vrow * 128 + (kcb ^ ((vrow & 7) << 4)));
        acc_o[mf] = __builtin_amdgcn_mfma_f32_16x16x32_bf16(av, pb, acc_o[mf], 0, 0, 0);
      }
    }
  }
  // l for column q=ln lives in lane ln (g==0), acc_o[8][0]; broadcast via shfl
  float l_t = __shfl(acc_o[8][0], ln, 64);
  float linv = 1.0f / l_t;
  int qg2 = q0 + wave * 16 + ln;
#pragma unroll
  for (int mf = 0; mf < 8; ++mf) {
    int dbase = mf * 16 + g * 4;
#pragma unroll
    for (int r = 0; r < 4; ++r) {
      out[((size_t)(b * 512 + h * 128 + dbase + r)) * 1024 + qg2] = acc_o[mf][r] * linv;
    }
  }
}

extern "C" void kernel_launch(void* const* d_in, const int* in_sizes, int n_in,
                              void* d_out, int out_size, void* d_ws, size_t ws_size,
                              hipStream_t stream) {
  const float* fm = (const float*)d_in[0];
  const float* wqk = (const float*)d_in[1];
  const float* wv = (const float*)d_in[2];
  const float* relh = (const float*)d_in[3];
  const float* relw = (const float*)d_in[4];
  float* out = (float*)d_out;
  char* w = (char*)d_ws;

  __hip_bfloat16* fmt = (__hip_bfloat16*)w;                   // 16 MB  [B][L][C]
  __hip_bfloat16* wall = (__hip_bfloat16*)(w + 16777216);     // 1.5 MB [1536][512]
  __hip_bfloat16* Qb = (__hip_bfloat16*)(w + 18350080);       // 16 MB  [B][H][L][D] (scaled*log2e)
  __hip_bfloat16* Kb = (__hip_bfloat16*)(w + 35127296);       // 16 MB  [B][H][L][D]
  __hip_bfloat16* Vt = (__hip_bfloat16*)(w + 51904512);       // 16 MB  [B][H][D][L]
  float* QRW = (float*)(w + 68681728);                        // 16 MB  [B][H][L][64]
  float* QRH = (float*)(w + 85458944);                        // 16 MB  [B][H][L][64]
  __hip_bfloat16* relsb = (__hip_bfloat16*)(w + 102236160);   // 32 KB  [2][64][128]

  k_convw<<<3136, 256, 0, stream>>>(wqk, wv, relw, relh, wall, relsb);
  k_tfm<<<dim3(16, 8, 16), 256, 0, stream>>>(fm, fmt);
  k_gemm<<<dim3(8, 12, 16), 256, 0, stream>>>(fmt, wall, Qb, Kb, Vt);
  k_bias<<<dim3(8, 64), 256, 0, stream>>>(Qb, relsb, QRW, QRH);
  k_attn<<<dim3(16, 64), 256, 78080, stream>>>(Qb, Kb, Vt, QRW, QRH, out);
}

// Round 8
// 144.238 us; speedup vs baseline: 2.3090x; 1.1000x over previous
//
#include <hip/hip_runtime.h>
#include <hip/hip_bf16.h>
#include <math.h>

typedef __bf16 bf16x8 __attribute__((ext_vector_type(8)));
typedef float f32x4 __attribute__((ext_vector_type(4)));

// QSCALE * log2(e): Q (and the bias tables derived from Q) live in the exp2
// domain, so softmax needs only exp2f.
#define QSCALE_L2E (0.08838834764831845f * 1.4426950408889634f)

static __device__ __forceinline__ unsigned short bits_bf16(float v) {
  __hip_bfloat16 h = __float2bfloat16(v);
  return *reinterpret_cast<unsigned short*>(&h);
}

// async global->LDS DMA, 16B per lane; LDS dest = wave-uniform base + lane*16
static __device__ __forceinline__ void gload16(const void* g, void* l) {
  __builtin_amdgcn_global_load_lds(
      (const __attribute__((address_space(1))) void*)g,
      (__attribute__((address_space(3))) void*)l, 16, 0, 0);
}

// ---------------- kernel 1: convert weights + rel tables to bf16 ----------------
__global__ __launch_bounds__(256) void k_convw(const float* __restrict__ wqk,
                                               const float* __restrict__ wv,
                                               const float* __restrict__ relw,
                                               const float* __restrict__ relh,
                                               __hip_bfloat16* __restrict__ wall,
                                               __hip_bfloat16* __restrict__ relsb) {
  int i = blockIdx.x * 256 + threadIdx.x;
  if (i < 1536 * 512) {
    float v = (i < 1024 * 512) ? wqk[i] : wv[i - 1024 * 512];
    wall[i] = __float2bfloat16(v);
  } else {
    int j = i - 1536 * 512;  // 0..16383 : [2][64][128], row 63 of each table = 0
    int t = j >> 13, m = (j >> 7) & 63, d = j & 127;
    float v = (m < 63) ? (t ? relh[m * 128 + d] : relw[m * 128 + d]) : 0.f;
    relsb[j] = __float2bfloat16(v);
  }
}

// ---------------- kernel 2: transpose + convert featuremap -> [B][L][C] bf16 ----------------
__global__ __launch_bounds__(256) void k_tfm(const float* __restrict__ fm,
                                             __hip_bfloat16* __restrict__ fmt) {
  __shared__ float t[64][65];
  int lt = blockIdx.x, ct = blockIdx.y, b = blockIdx.z;
  int tid = threadIdx.x;
  const float* src = fm + ((size_t)b * 512 + ct * 64) * 1024 + lt * 64;
#pragma unroll
  for (int i = 0; i < 16; ++i) {
    int idx = i * 256 + tid;
    int r = idx >> 6, cl = idx & 63;
    t[r][cl] = src[(size_t)r * 1024 + cl];
  }
  __syncthreads();
  __hip_bfloat16* dst = fmt + ((size_t)b * 1024 + lt * 64) * 512 + ct * 64;
#pragma unroll
  for (int i = 0; i < 16; ++i) {
    int idx = i * 256 + tid;
    int r = idx >> 6, cc = idx & 63;
    dst[(size_t)r * 512 + cc] = __float2bfloat16(t[cc][r]);
  }
}

// ---------------- kernel 3: QKV projection GEMM (m97 structure) ----------------
__global__ __launch_bounds__(256) void k_gemm(const __hip_bfloat16* __restrict__ fmt,
                                              const __hip_bfloat16* __restrict__ wall,
                                              __hip_bfloat16* __restrict__ Qb,
                                              __hip_bfloat16* __restrict__ Kb,
                                              __hip_bfloat16* __restrict__ Vt) {
  __shared__ char smem[32768];
  char* As = smem;
  char* Bs = smem + 16384;
  int bm = blockIdx.x, bn = blockIdx.y, b = blockIdx.z;
  int tid = threadIdx.x;
  int lane = tid & 63, wave = tid >> 6;
  int wr = wave >> 1, wc = wave & 1;
  int g = lane >> 4, ln = lane & 15;
  const char* Ag = (const char*)(fmt + ((size_t)b * 1024 + bm * 128) * 512);
  const char* Bg = (const char*)(wall + (size_t)bn * 128 * 512);

  int j3 = lane >> 3, j7 = lane & 7;
  int segsrc = ((j7 ^ j3) << 4);  // pre-swizzled source seg (row&7 == j3)

  f32x4 acc[4][4] = {};
  for (int kb = 0; kb < 8; ++kb) {
#pragma unroll
    for (int i = 0; i < 4; ++i) {
      int R = (wave * 4 + i) * 8;  // 8 rows per 1KB DMA
      size_t go = (size_t)(R + j3) * 1024 + (size_t)kb * 128 + segsrc;
      gload16(Ag + go, As + R * 128);
      gload16(Bg + go, Bs + R * 128);
    }
    __syncthreads();
#pragma unroll
    for (int ks = 0; ks < 2; ++ks) {
      int kcol = ks * 64 + (g << 4);
      bf16x8 af[4], bfr[4];
#pragma unroll
      for (int m = 0; m < 4; ++m) {
        int row = wr * 64 + m * 16 + ln;
        af[m] = *(const bf16x8*)(As + row * 128 + (kcol ^ ((ln & 7) << 4)));
      }
#pragma unroll
      for (int n = 0; n < 4; ++n) {
        int row = wc * 64 + n * 16 + ln;
        bfr[n] = *(const bf16x8*)(Bs + row * 128 + (kcol ^ ((ln & 7) << 4)));
      }
#pragma unroll
      for (int m = 0; m < 4; ++m)
#pragma unroll
        for (int n = 0; n < 4; ++n)
          acc[m][n] = __builtin_amdgcn_mfma_f32_16x16x32_bf16(af[m], bfr[n], acc[m][n], 0, 0, 0);
    }
    __syncthreads();
  }

  // ---- epilogue: restage C tile in LDS, then coalesced row stores ----
  int otype = bn >> 2;  // 0=q, 1=k, 2=v
  int head = bn & 3;
  if (otype != 2) {
    float sc = (otype == 0) ? QSCALE_L2E : 1.0f;
#pragma unroll
    for (int m = 0; m < 4; ++m)
#pragma unroll
      for (int n = 0; n < 4; ++n) {
        int d = wc * 64 + n * 16 + ln;
#pragma unroll
        for (int r = 0; r < 4; ++r) {
          int l = wr * 64 + m * 16 + g * 4 + r;
          *(__hip_bfloat16*)(smem + l * 256 + ((d * 2) ^ ((l & 7) << 4))) =
              __float2bfloat16(acc[m][n][r] * sc);
        }
      }
    __syncthreads();
    __hip_bfloat16* dstb =
        (otype == 0 ? Qb : Kb) + (((size_t)(b * 4 + head) * 1024) + bm * 128) * 128;
#pragma unroll
    for (int i = 0; i < 8; ++i) {
      int idx = i * 256 + tid;
      int row = idx >> 4, c16 = idx & 15;
      uint4 v = *(const uint4*)(smem + row * 256 + ((c16 * 16) ^ ((row & 7) << 4)));
      *(uint4*)(dstb + (size_t)row * 128 + c16 * 8) = v;
    }
  } else {
#pragma unroll
    for (int m = 0; m < 4; ++m)
#pragma unroll
      for (int n = 0; n < 4; ++n) {
        int d = wc * 64 + n * 16 + ln;
        int lbase = wr * 64 + m * 16 + g * 4;
        ushort4 pk;
        pk.x = bits_bf16(acc[m][n][0]);
        pk.y = bits_bf16(acc[m][n][1]);
        pk.z = bits_bf16(acc[m][n][2]);
        pk.w = bits_bf16(acc[m][n][3]);
        *(ushort4*)(smem + d * 256 + ((lbase * 2) ^ ((d & 7) << 4))) = pk;
      }
    __syncthreads();
    __hip_bfloat16* dstb = Vt + ((size_t)(b * 4 + head) * 128) * 1024 + bm * 128;
#pragma unroll
    for (int i = 0; i < 8; ++i) {
      int idx = i * 256 + tid;
      int row = idx >> 4, c16 = idx & 15;
      uint4 v = *(const uint4*)(smem + row * 256 + ((c16 * 16) ^ ((row & 7) << 4)));
      *(uint4*)(dstb + (size_t)row * 1024 + c16 * 8) = v;
    }
  }
}

// ---------------- kernel 4: bias tables via MFMA ----------------
// Tables inherit the log2e factor from Qb automatically.
__global__ __launch_bounds__(256) void k_bias(const __hip_bfloat16* __restrict__ Qb,
                                              const __hip_bfloat16* __restrict__ relsb,
                                              float* __restrict__ QRW,
                                              float* __restrict__ QRH) {
  __shared__ char sh[32768];  // [2][64][128] bf16, swizzled
  int bx = blockIdx.x, bh = blockIdx.y;
  int tid = threadIdx.x, lane = tid & 63, wave = tid >> 6;
  int g = lane >> 4, ln = lane & 15;
#pragma unroll
  for (int i = 0; i < 8; ++i) {
    int chunk = i * 256 + tid;
    int row = chunk >> 4, c16 = chunk & 15;
    *(uint4*)(sh + row * 256 + ((c16 * 16) ^ ((row & 7) << 4))) =
        *(const uint4*)(relsb + (size_t)row * 128 + c16 * 8);
  }
  __syncthreads();
  size_t bhL = (size_t)bh * 1024;
  int l0 = bx * 128 + wave * 32;
  const __hip_bfloat16* Qg = Qb + (bhL + l0) * 128;
  bf16x8 a[2][4];
#pragma unroll
  for (int lf = 0; lf < 2; ++lf)
#pragma unroll
    for (int ks = 0; ks < 4; ++ks)
      a[lf][ks] = *(const bf16x8*)(Qg + (size_t)(lf * 16 + ln) * 128 + ks * 32 + g * 8);
#pragma unroll
  for (int t = 0; t < 2; ++t) {
    float* dst = (t == 0 ? QRW : QRH) + (bhL + l0) * 64;
#pragma unroll
    for (int n = 0; n < 4; ++n) {
      f32x4 acc2[2] = {};
#pragma unroll
      for (int ks = 0; ks < 4; ++ks) {
        int mrow = n * 16 + ln;
        bf16x8 bf = *(const bf16x8*)(sh + t * 16384 + mrow * 256 +
                                     ((ks * 64 + g * 16) ^ ((mrow & 7) << 4)));
#pragma unroll
        for (int lf = 0; lf < 2; ++lf)
          acc2[lf] = __builtin_amdgcn_mfma_f32_16x16x32_bf16(a[lf][ks], bf, acc2[lf], 0, 0, 0);
      }
#pragma unroll
      for (int lf = 0; lf < 2; ++lf)
#pragma unroll
        for (int r = 0; r < 4; ++r)
          dst[(size_t)(lf * 16 + g * 4 + r) * 64 + n * 16 + ln] = acc2[lf][r];
    }
  }
}

// ---------------- kernel 5: fused attention (swapped QK^T) ----------------
// S^T = mfma(K, Q): lane holds S[key = n*16+g*4+r][q = wave*16+ln] -> softmax
// stats are per-lane scalars (reduce across g via 2 shfl), alpha/l apply
// in-lane, P-write packs 4 keys per ushort4. Same LDS reads as before.
__global__ __launch_bounds__(256) void k_attn(const __hip_bfloat16* __restrict__ Qb,
                                              const __hip_bfloat16* __restrict__ Kb,
                                              const __hip_bfloat16* __restrict__ Vt,
                                              const float* __restrict__ QRW,
                                              const float* __restrict__ QRH,
                                              float* __restrict__ out) {
  extern __shared__ char smem[];
  float* qrw_s = (float*)smem;               // [64][68] f32  17408 B
  float* qrh_s = (float*)(smem + 17408);     // [64][68] f32  17408 B
  char* kv = smem + 34816;                   // K tile [64][256B] (also Q stage) 16384 B
  char* vtl = smem + 51200;                  // V_t tile [128][128B] 16384 B
  char* pt = smem + 67584;                   // P [4 waves][16][128B] 8192 B
                                             // total 75776 B

  int qt = blockIdx.x, bh = blockIdx.y;
  int b = bh >> 2, h = bh & 3;
  int tid = threadIdx.x, lane = tid & 63, wave = tid >> 6;
  int g = lane >> 4, ln = lane & 15;
  int q0 = qt * 64;
  size_t bhL = (size_t)bh * 1024;

  // stage Q tile via gload_lds (pre-swizzled source, LDS linear)
  const char* Qg = (const char*)(Qb + (bhL + q0) * 128);
#pragma unroll
  for (int i = 0; i < 4; ++i) {
    int R = (wave * 4 + i) * 4;
    int seg = ((lane & 15) ^ (((i & 1) * 4) + (lane >> 4))) << 4;
    gload16(Qg + (size_t)(R + (lane >> 4)) * 256 + seg, kv + R * 256);
  }
  // stage bias tables [64 q][64 m], stride 68
#pragma unroll
  for (int i = 0; i < 4; ++i) {
    int chunk = i * 256 + tid;
    int row = chunk >> 4, c16 = chunk & 15;
    *(uint4*)(qrw_s + row * 68 + c16 * 4) =
        *(const uint4*)(QRW + (bhL + q0 + row) * 64 + c16 * 4);
    *(uint4*)(qrh_s + row * 68 + c16 * 4) =
        *(const uint4*)(QRH + (bhL + q0 + row) * 64 + c16 * 4);
  }
  __syncthreads();

  bf16x8 qa[4];
  int qloc = wave * 16 + ln;
#pragma unroll
  for (int ks = 0; ks < 4; ++ks)
    qa[ks] = *(const bf16x8*)(kv + qloc * 256 + ((ks * 64 + (g << 4)) ^ ((qloc & 7) << 4)));

  // per-lane bias: q = qloc fixed; key = kt*64 + n*16 + g*4 + r
  // cy = (n&1)*16 + g*4 + r (kt-invariant), ry = 2kt + (n>>1)
  int qg2 = q0 + qloc;
  int cx = qg2 & 31, rx = qg2 >> 5;
  float wb[2][4];
#pragma unroll
  for (int half = 0; half < 2; ++half)
#pragma unroll
    for (int r = 0; r < 4; ++r)
      wb[half][r] = qrw_s[qloc * 68 + (half * 16 + g * 4 + r - cx + 31)];
  const float* hptr = qrh_s + qloc * 68 + (31 - rx);

  f32x4 acc_o[8] = {};
  float mrow = -1e30f, lrow = 0.f;
  char* pw = pt + wave * 2048;
  const char* Kg0 = (const char*)(Kb + bhL * 128);
  const char* Vg0 = (const char*)(Vt + (size_t)bh * 128 * 1024);
  int j3 = lane >> 3, j7 = lane & 7;
  int segv = ((j7 ^ j3) << 4);

  for (int kt = 0; kt < 16; ++kt) {
    __syncthreads();  // prior reads of kv/vtl done
    const char* Kg = Kg0 + (size_t)kt * 64 * 256;
#pragma unroll
    for (int i = 0; i < 4; ++i) {
      int R = (wave * 4 + i) * 4;
      int seg = ((lane & 15) ^ (((i & 1) * 4) + (lane >> 4))) << 4;
      gload16(Kg + (size_t)(R + (lane >> 4)) * 256 + seg, kv + R * 256);
    }
    const char* Vg = Vg0 + (size_t)kt * 128;
#pragma unroll
    for (int i = 0; i < 4; ++i) {
      int R = (wave * 4 + i) * 8;
      gload16(Vg + (size_t)(R + j3) * 2048 + segv, vtl + R * 128);
    }
    __syncthreads();

    // S^T = K Q^T  (log2 domain): s[n][r] = S[key=n*16+g*4+r][q=qloc]
    f32x4 s[4] = {};
#pragma unroll
    for (int ks = 0; ks < 4; ++ks) {
      int kcol = ks * 64 + (g << 4);
#pragma unroll
      for (int n = 0; n < 4; ++n) {
        int krow = n * 16 + ln;
        bf16x8 kf = *(const bf16x8*)(kv + krow * 256 + (kcol ^ ((krow & 7) << 4)));
        s[n] = __builtin_amdgcn_mfma_f32_16x16x32_bf16(kf, qa[ks], s[n], 0, 0, 0);
      }
    }
    // + bias from registers
    float hb0 = hptr[kt * 2], hb1 = hptr[kt * 2 + 1];
#pragma unroll
    for (int n = 0; n < 4; ++n) {
      float hb = (n >> 1) ? hb1 : hb0;
#pragma unroll
      for (int r = 0; r < 4; ++r) s[n][r] += wb[n & 1][r] + hb;
    }
    // online softmax: per-lane scalar stats for q=qloc, reduce across g
    float mt = s[0][0];
#pragma unroll
    for (int n = 0; n < 4; ++n)
#pragma unroll
      for (int r = 0; r < 4; ++r) mt = fmaxf(mt, s[n][r]);
    mt = fmaxf(mt, __shfl_xor(mt, 16, 64));
    mt = fmaxf(mt, __shfl_xor(mt, 32, 64));
    float mn = fmaxf(mrow, mt);
    float alpha = exp2f(mrow - mn);
    mrow = mn;
    float rs = 0.f;
#pragma unroll
    for (int n = 0; n < 4; ++n)
#pragma unroll
      for (int r = 0; r < 4; ++r) {
        s[n][r] = exp2f(s[n][r] - mrow);
        rs += s[n][r];
      }
    rs += __shfl_xor(rs, 16, 64);
    rs += __shfl_xor(rs, 32, 64);
    lrow = lrow * alpha + rs;
#pragma unroll
    for (int mf = 0; mf < 8; ++mf) acc_o[mf] *= alpha;
    // write P[q=qloc][key] packed: 4 consecutive keys per ushort4
#pragma unroll
    for (int n = 0; n < 4; ++n) {
      ushort4 pk;
      pk.x = bits_bf16(s[n][0]);
      pk.y = bits_bf16(s[n][1]);
      pk.z = bits_bf16(s[n][2]);
      pk.w = bits_bf16(s[n][3]);
      *(ushort4*)(pw + ln * 128 + ((n * 32 + g * 8) ^ ((ln & 7) << 4))) = pk;
    }
    // PV (transposed): acc_o[d][q] += V_t . P^T
#pragma unroll
    for (int ks2 = 0; ks2 < 2; ++ks2) {
      int kcb = ks2 * 64 + (g << 4);
      bf16x8 pb = *(const bf16x8*)(pw + ln * 128 + (kcb ^ ((ln & 7) << 4)));
#pragma unroll
      for (int mf = 0; mf < 8; ++mf) {
        int vrow = mf * 16 + ln;
        bf16x8 av = *(const bf16x8*)(vtl + vrow * 128 + (kcb ^ ((vrow & 7) << 4)));
        acc_o[mf] = __builtin_amdgcn_mfma_f32_16x16x32_bf16(av, pb, acc_o[mf], 0, 0, 0);
      }
    }
  }
  // l is in-lane (stats for q=qloc); acc columns are q=qloc
  float linv = 1.0f / lrow;
  int qg3 = q0 + wave * 16 + ln;
#pragma unroll
  for (int mf = 0; mf < 8; ++mf) {
    int dbase = mf * 16 + g * 4;
#pragma unroll
    for (int r = 0; r < 4; ++r) {
      out[((size_t)(b * 512 + h * 128 + dbase + r)) * 1024 + qg3] = acc_o[mf][r] * linv;
    }
  }
}

extern "C" void kernel_launch(void* const* d_in, const int* in_sizes, int n_in,
                              void* d_out, int out_size, void* d_ws, size_t ws_size,
                              hipStream_t stream) {
  const float* fm = (const float*)d_in[0];
  const float* wqk = (const float*)d_in[1];
  const float* wv = (const float*)d_in[2];
  const float* relh = (const float*)d_in[3];
  const float* relw = (const float*)d_in[4];
  float* out = (float*)d_out;
  char* w = (char*)d_ws;

  __hip_bfloat16* fmt = (__hip_bfloat16*)w;                   // 16 MB  [B][L][C]
  __hip_bfloat16* wall = (__hip_bfloat16*)(w + 16777216);     // 1.5 MB [1536][512]
  __hip_bfloat16* Qb = (__hip_bfloat16*)(w + 18350080);       // 16 MB  [B][H][L][D] (scaled*log2e)
  __hip_bfloat16* Kb = (__hip_bfloat16*)(w + 35127296);       // 16 MB  [B][H][L][D]
  __hip_bfloat16* Vt = (__hip_bfloat16*)(w + 51904512);       // 16 MB  [B][H][D][L]
  float* QRW = (float*)(w + 68681728);                        // 16 MB  [B][H][L][64]
  float* QRH = (float*)(w + 85458944);                        // 16 MB  [B][H][L][64]
  __hip_bfloat16* relsb = (__hip_bfloat16*)(w + 102236160);   // 32 KB  [2][64][128]

  k_convw<<<3136, 256, 0, stream>>>(wqk, wv, relw, relh, wall, relsb);
  k_tfm<<<dim3(16, 8, 16), 256, 0, stream>>>(fm, fmt);
  k_gemm<<<dim3(8, 12, 16), 256, 0, stream>>>(fmt, wall, Qb, Kb, Vt);
  k_bias<<<dim3(8, 64), 256, 0, stream>>>(Qb, relsb, QRW, QRH);
  k_attn<<<dim3(16, 64), 256, 75776, stream>>>(Qb, Kb, Vt, QRW, QRH, out);
}

// Round 9
// 132.122 us; speedup vs baseline: 2.5207x; 1.0917x over previous
//
#include <hip/hip_runtime.h>
#include <hip/hip_bf16.h>
#include <math.h>

typedef __bf16 bf16x8 __attribute__((ext_vector_type(8)));
typedef float f32x4 __attribute__((ext_vector_type(4)));

// QSCALE * log2(e): Q (and the bias tables derived from Q) live in the exp2
// domain, so softmax needs only exp2f.
#define QSCALE_L2E (0.08838834764831845f * 1.4426950408889634f)

static __device__ __forceinline__ unsigned short bits_bf16(float v) {
  __hip_bfloat16 h = __float2bfloat16(v);
  return *reinterpret_cast<unsigned short*>(&h);
}

// async global->LDS DMA, 16B per lane; LDS dest = wave-uniform base + lane*16
static __device__ __forceinline__ void gload16(const void* g, void* l) {
  __builtin_amdgcn_global_load_lds(
      (const __attribute__((address_space(1))) void*)g,
      (__attribute__((address_space(3))) void*)l, 16, 0, 0);
}

// ---------------- kernel 1: convert weights + rel tables to bf16 ----------------
__global__ __launch_bounds__(256) void k_convw(const float* __restrict__ wqk,
                                               const float* __restrict__ wv,
                                               const float* __restrict__ relw,
                                               const float* __restrict__ relh,
                                               __hip_bfloat16* __restrict__ wall,
                                               __hip_bfloat16* __restrict__ relsb) {
  int i = blockIdx.x * 256 + threadIdx.x;
  if (i < 1536 * 512) {
    float v = (i < 1024 * 512) ? wqk[i] : wv[i - 1024 * 512];
    wall[i] = __float2bfloat16(v);
  } else {
    int j = i - 1536 * 512;  // 0..16383 : [2][64][128], row 63 of each table = 0
    int t = j >> 13, m = (j >> 7) & 63, d = j & 127;
    float v = (m < 63) ? (t ? relh[m * 128 + d] : relw[m * 128 + d]) : 0.f;
    relsb[j] = __float2bfloat16(v);
  }
}

// ---------------- kernel 2: transpose + convert featuremap -> [B][L][C] bf16 ----------------
__global__ __launch_bounds__(256) void k_tfm(const float* __restrict__ fm,
                                             __hip_bfloat16* __restrict__ fmt) {
  __shared__ float t[64][65];
  int lt = blockIdx.x, ct = blockIdx.y, b = blockIdx.z;
  int tid = threadIdx.x;
  const float* src = fm + ((size_t)b * 512 + ct * 64) * 1024 + lt * 64;
#pragma unroll
  for (int i = 0; i < 16; ++i) {
    int idx = i * 256 + tid;
    int r = idx >> 6, cl = idx & 63;
    t[r][cl] = src[(size_t)r * 1024 + cl];
  }
  __syncthreads();
  __hip_bfloat16* dst = fmt + ((size_t)b * 1024 + lt * 64) * 512 + ct * 64;
#pragma unroll
  for (int i = 0; i < 16; ++i) {
    int idx = i * 256 + tid;
    int r = idx >> 6, cc = idx & 63;
    dst[(size_t)r * 512 + cc] = __float2bfloat16(t[cc][r]);
  }
}

// ---------------- kernel 3: QKV projection GEMM (m97 structure) ----------------
__global__ __launch_bounds__(256) void k_gemm(const __hip_bfloat16* __restrict__ fmt,
                                              const __hip_bfloat16* __restrict__ wall,
                                              __hip_bfloat16* __restrict__ Qb,
                                              __hip_bfloat16* __restrict__ Kb,
                                              __hip_bfloat16* __restrict__ Vt) {
  __shared__ char smem[32768];
  char* As = smem;
  char* Bs = smem + 16384;
  int bm = blockIdx.x, bn = blockIdx.y, b = blockIdx.z;
  int tid = threadIdx.x;
  int lane = tid & 63, wave = tid >> 6;
  int wr = wave >> 1, wc = wave & 1;
  int g = lane >> 4, ln = lane & 15;
  const char* Ag = (const char*)(fmt + ((size_t)b * 1024 + bm * 128) * 512);
  const char* Bg = (const char*)(wall + (size_t)bn * 128 * 512);

  int j3 = lane >> 3, j7 = lane & 7;
  int segsrc = ((j7 ^ j3) << 4);  // pre-swizzled source seg (row&7 == j3)

  f32x4 acc[4][4] = {};
  for (int kb = 0; kb < 8; ++kb) {
#pragma unroll
    for (int i = 0; i < 4; ++i) {
      int R = (wave * 4 + i) * 8;  // 8 rows per 1KB DMA
      size_t go = (size_t)(R + j3) * 1024 + (size_t)kb * 128 + segsrc;
      gload16(Ag + go, As + R * 128);
      gload16(Bg + go, Bs + R * 128);
    }
    __syncthreads();
#pragma unroll
    for (int ks = 0; ks < 2; ++ks) {
      int kcol = ks * 64 + (g << 4);
      bf16x8 af[4], bfr[4];
#pragma unroll
      for (int m = 0; m < 4; ++m) {
        int row = wr * 64 + m * 16 + ln;
        af[m] = *(const bf16x8*)(As + row * 128 + (kcol ^ ((ln & 7) << 4)));
      }
#pragma unroll
      for (int n = 0; n < 4; ++n) {
        int row = wc * 64 + n * 16 + ln;
        bfr[n] = *(const bf16x8*)(Bs + row * 128 + (kcol ^ ((ln & 7) << 4)));
      }
#pragma unroll
      for (int m = 0; m < 4; ++m)
#pragma unroll
        for (int n = 0; n < 4; ++n)
          acc[m][n] = __builtin_amdgcn_mfma_f32_16x16x32_bf16(af[m], bfr[n], acc[m][n], 0, 0, 0);
    }
    __syncthreads();
  }

  // ---- epilogue: restage C tile in LDS, then coalesced row stores ----
  int otype = bn >> 2;  // 0=q, 1=k, 2=v
  int head = bn & 3;
  if (otype != 2) {
    float sc = (otype == 0) ? QSCALE_L2E : 1.0f;
#pragma unroll
    for (int m = 0; m < 4; ++m)
#pragma unroll
      for (int n = 0; n < 4; ++n) {
        int d = wc * 64 + n * 16 + ln;
#pragma unroll
        for (int r = 0; r < 4; ++r) {
          int l = wr * 64 + m * 16 + g * 4 + r;
          *(__hip_bfloat16*)(smem + l * 256 + ((d * 2) ^ ((l & 7) << 4))) =
              __float2bfloat16(acc[m][n][r] * sc);
        }
      }
    __syncthreads();
    __hip_bfloat16* dstb =
        (otype == 0 ? Qb : Kb) + (((size_t)(b * 4 + head) * 1024) + bm * 128) * 128;
#pragma unroll
    for (int i = 0; i < 8; ++i) {
      int idx = i * 256 + tid;
      int row = idx >> 4, c16 = idx & 15;
      uint4 v = *(const uint4*)(smem + row * 256 + ((c16 * 16) ^ ((row & 7) << 4)));
      *(uint4*)(dstb + (size_t)row * 128 + c16 * 8) = v;
    }
  } else {
#pragma unroll
    for (int m = 0; m < 4; ++m)
#pragma unroll
      for (int n = 0; n < 4; ++n) {
        int d = wc * 64 + n * 16 + ln;
        int lbase = wr * 64 + m * 16 + g * 4;
        ushort4 pk;
        pk.x = bits_bf16(acc[m][n][0]);
        pk.y = bits_bf16(acc[m][n][1]);
        pk.z = bits_bf16(acc[m][n][2]);
        pk.w = bits_bf16(acc[m][n][3]);
        *(ushort4*)(smem + d * 256 + ((lbase * 2) ^ ((d & 7) << 4))) = pk;
      }
    __syncthreads();
    __hip_bfloat16* dstb = Vt + ((size_t)(b * 4 + head) * 128) * 1024 + bm * 128;
#pragma unroll
    for (int i = 0; i < 8; ++i) {
      int idx = i * 256 + tid;
      int row = idx >> 4, c16 = idx & 15;
      uint4 v = *(const uint4*)(smem + row * 256 + ((c16 * 16) ^ ((row & 7) << 4)));
      *(uint4*)(dstb + (size_t)row * 1024 + c16 * 8) = v;
    }
  }
}

// ---------------- kernel 4: bias tables via MFMA ----------------
// Tables inherit the log2e factor from Qb automatically.
__global__ __launch_bounds__(256) void k_bias(const __hip_bfloat16* __restrict__ Qb,
                                              const __hip_bfloat16* __restrict__ relsb,
                                              float* __restrict__ QRW,
                                              float* __restrict__ QRH) {
  __shared__ char sh[32768];  // [2][64][128] bf16, swizzled
  int bx = blockIdx.x, bh = blockIdx.y;
  int tid = threadIdx.x, lane = tid & 63, wave = tid >> 6;
  int g = lane >> 4, ln = lane & 15;
#pragma unroll
  for (int i = 0; i < 8; ++i) {
    int chunk = i * 256 + tid;
    int row = chunk >> 4, c16 = chunk & 15;
    *(uint4*)(sh + row * 256 + ((c16 * 16) ^ ((row & 7) << 4))) =
        *(const uint4*)(relsb + (size_t)row * 128 + c16 * 8);
  }
  __syncthreads();
  size_t bhL = (size_t)bh * 1024;
  int l0 = bx * 128 + wave * 32;
  const __hip_bfloat16* Qg = Qb + (bhL + l0) * 128;
  bf16x8 a[2][4];
#pragma unroll
  for (int lf = 0; lf < 2; ++lf)
#pragma unroll
    for (int ks = 0; ks < 4; ++ks)
      a[lf][ks] = *(const bf16x8*)(Qg + (size_t)(lf * 16 + ln) * 128 + ks * 32 + g * 8);
#pragma unroll
  for (int t = 0; t < 2; ++t) {
    float* dst = (t == 0 ? QRW : QRH) + (bhL + l0) * 64;
#pragma unroll
    for (int n = 0; n < 4; ++n) {
      f32x4 acc2[2] = {};
#pragma unroll
      for (int ks = 0; ks < 4; ++ks) {
        int mrow = n * 16 + ln;
        bf16x8 bf = *(const bf16x8*)(sh + t * 16384 + mrow * 256 +
                                     ((ks * 64 + g * 16) ^ ((mrow & 7) << 4)));
#pragma unroll
        for (int lf = 0; lf < 2; ++lf)
          acc2[lf] = __builtin_amdgcn_mfma_f32_16x16x32_bf16(a[lf][ks], bf, acc2[lf], 0, 0, 0);
      }
#pragma unroll
      for (int lf = 0; lf < 2; ++lf)
#pragma unroll
        for (int r = 0; r < 4; ++r)
          dst[(size_t)(lf * 16 + g * 4 + r) * 64 + n * 16 + ln] = acc2[lf][r];
    }
  }
}

// ---------------- kernel 5: fused attention (swapped QK^T, 32 q/wave) ----------------
// Block = 128 queries, 4 waves x 32 q (2 q-sets). K/V fragment reads are
// q-invariant -> amortized over 2x MFMA. Q/wb direct global->reg; hb in a
// compact [128][40] f32 LDS window; online softmax per-lane (r8-verified).
__global__ __launch_bounds__(256, 2) void k_attn(const __hip_bfloat16* __restrict__ Qb,
                                                 const __hip_bfloat16* __restrict__ Kb,
                                                 const __hip_bfloat16* __restrict__ Vt,
                                                 const float* __restrict__ QRW,
                                                 const float* __restrict__ QRH,
                                                 float* __restrict__ out) {
  extern __shared__ char smem[];
  float* hb_s = (float*)smem;                // [128][40] f32 = 20480 B
  char* kv = smem + 20480;                   // K tile [64][256B] 16384 B
  char* vtl = smem + 36864;                  // V_t tile [128][128B] 16384 B
  char* pt = smem + 53248;                   // P [4 waves][32][128B] 16384 B
                                             // total 69632 B

  int qt = blockIdx.x, bh = blockIdx.y;
  int b = bh >> 2, h = bh & 3;
  int tid = threadIdx.x, lane = tid & 63, wave = tid >> 6;
  int g = lane >> 4, ln = lane & 15;
  int q0 = qt * 128;
  size_t bhL = (size_t)bh * 1024;

  // stage hb rows: aligned 36-float window of QRH per q-row (start = (31-rx)&~3)
#pragma unroll
  for (int i = 0; i < 5; ++i) {
    int c = i * 256 + tid;  // 128 rows x 9 chunks = 1152
    if (c < 1152) {
      int row = c / 9, j = c % 9;
      int s0 = (31 - ((q0 + row) >> 5)) & ~3;
      *(uint4*)(hb_s + row * 40 + j * 4) =
          *(const uint4*)(QRH + (bhL + q0 + row) * 64 + s0 + j * 4);
    }
  }

  // per-q-set constants + direct global->reg loads (one-time)
  bf16x8 qa[2][4];
  float wb[2][2][4];
  int qloc[2], hbase[2];
#pragma unroll
  for (int u = 0; u < 2; ++u) {
    qloc[u] = wave * 32 + u * 16 + ln;
    int qg = q0 + qloc[u];
    int cx = qg & 31, rx = qg >> 5;
    hbase[u] = (31 - rx) & 3;
    const __hip_bfloat16* qrow = Qb + (bhL + qg) * 128;
#pragma unroll
    for (int ks = 0; ks < 4; ++ks)
      qa[u][ks] = *(const bf16x8*)(qrow + ks * 32 + g * 8);
    const float* wrow = QRW + (bhL + qg) * 64 + (31 - cx) + g * 4;
#pragma unroll
    for (int half = 0; half < 2; ++half)
#pragma unroll
      for (int r = 0; r < 4; ++r) wb[u][half][r] = wrow[half * 16 + r];
  }

  f32x4 acc[2][8] = {};
  float mrow[2] = {-1e30f, -1e30f}, lrow[2] = {0.f, 0.f};
  char* pw = pt + wave * 4096;
  const char* Kg0 = (const char*)(Kb + bhL * 128);
  const char* Vg0 = (const char*)(Vt + (size_t)bh * 128 * 1024);
  int j3 = lane >> 3, j7 = lane & 7;
  int segv = ((j7 ^ j3) << 4);

  for (int kt = 0; kt < 16; ++kt) {
    __syncthreads();  // prior reads of kv/vtl done (kt=0: hb_s stage visible after next barrier)
    const char* Kg = Kg0 + (size_t)kt * 64 * 256;
#pragma unroll
    for (int i = 0; i < 4; ++i) {
      int R = (wave * 4 + i) * 4;
      int seg = ((lane & 15) ^ (((i & 1) * 4) + (lane >> 4))) << 4;
      gload16(Kg + (size_t)(R + (lane >> 4)) * 256 + seg, kv + R * 256);
    }
    const char* Vg = Vg0 + (size_t)kt * 128;
#pragma unroll
    for (int i = 0; i < 4; ++i) {
      int R = (wave * 4 + i) * 8;
      gload16(Vg + (size_t)(R + j3) * 2048 + segv, vtl + R * 128);
    }
    __syncthreads();

    // S^T = K Q^T (log2 domain): s[u][n][r] = S[key=n*16+g*4+r][q=qloc[u]]
    f32x4 s[2][4] = {};
#pragma unroll
    for (int ks = 0; ks < 4; ++ks) {
      int kcol = ks * 64 + (g << 4);
#pragma unroll
      for (int n = 0; n < 4; ++n) {
        int krow = n * 16 + ln;
        bf16x8 kf = *(const bf16x8*)(kv + krow * 256 + (kcol ^ ((krow & 7) << 4)));
        s[0][n] = __builtin_amdgcn_mfma_f32_16x16x32_bf16(kf, qa[0][ks], s[0][n], 0, 0, 0);
        s[1][n] = __builtin_amdgcn_mfma_f32_16x16x32_bf16(kf, qa[1][ks], s[1][n], 0, 0, 0);
      }
    }
    // bias + online softmax + P write, per q-set
#pragma unroll
    for (int u = 0; u < 2; ++u) {
      float hb0 = hb_s[qloc[u] * 40 + hbase[u] + kt * 2];
      float hb1 = hb_s[qloc[u] * 40 + hbase[u] + kt * 2 + 1];
#pragma unroll
      for (int n = 0; n < 4; ++n) {
        float hb = (n >> 1) ? hb1 : hb0;
#pragma unroll
        for (int r = 0; r < 4; ++r) s[u][n][r] += wb[u][n & 1][r] + hb;
      }
      float mt = s[u][0][0];
#pragma unroll
      for (int n = 0; n < 4; ++n)
#pragma unroll
        for (int r = 0; r < 4; ++r) mt = fmaxf(mt, s[u][n][r]);
      mt = fmaxf(mt, __shfl_xor(mt, 16, 64));
      mt = fmaxf(mt, __shfl_xor(mt, 32, 64));
      float mn = fmaxf(mrow[u], mt);
      float alpha = exp2f(mrow[u] - mn);
      mrow[u] = mn;
      float rs = 0.f;
#pragma unroll
      for (int n = 0; n < 4; ++n)
#pragma unroll
        for (int r = 0; r < 4; ++r) {
          s[u][n][r] = exp2f(s[u][n][r] - mn);
          rs += s[u][n][r];
        }
      rs += __shfl_xor(rs, 16, 64);
      rs += __shfl_xor(rs, 32, 64);
      lrow[u] = lrow[u] * alpha + rs;
#pragma unroll
      for (int mf = 0; mf < 8; ++mf) acc[u][mf] *= alpha;
#pragma unroll
      for (int n = 0; n < 4; ++n) {
        ushort4 pk;
        pk.x = bits_bf16(s[u][n][0]);
        pk.y = bits_bf16(s[u][n][1]);
        pk.z = bits_bf16(s[u][n][2]);
        pk.w = bits_bf16(s[u][n][3]);
        *(ushort4*)(pw + (u * 16 + ln) * 128 + ((n * 32 + g * 8) ^ ((ln & 7) << 4))) = pk;
      }
    }
    // PV (transposed): acc[u][d][q] += V_t . P^T ; av shared across both q-sets
#pragma unroll
    for (int ks2 = 0; ks2 < 2; ++ks2) {
      int kcb = ks2 * 64 + (g << 4);
      bf16x8 pb0 = *(const bf16x8*)(pw + ln * 128 + (kcb ^ ((ln & 7) << 4)));
      bf16x8 pb1 = *(const bf16x8*)(pw + (16 + ln) * 128 + (kcb ^ ((ln & 7) << 4)));
#pragma unroll
      for (int mf = 0; mf < 8; ++mf) {
        int vrow = mf * 16 + ln;
        bf16x8 av = *(const bf16x8*)(vtl + vrow * 128 + (kcb ^ ((vrow & 7) << 4)));
        acc[0][mf] = __builtin_amdgcn_mfma_f32_16x16x32_bf16(av, pb0, acc[0][mf], 0, 0, 0);
        acc[1][mf] = __builtin_amdgcn_mfma_f32_16x16x32_bf16(av, pb1, acc[1][mf], 0, 0, 0);
      }
    }
  }
  // normalize + store (l and acc columns are in-lane per q-set)
#pragma unroll
  for (int u = 0; u < 2; ++u) {
    float linv = 1.0f / lrow[u];
    int qg3 = q0 + wave * 32 + u * 16 + ln;
#pragma unroll
    for (int mf = 0; mf < 8; ++mf) {
      int dbase = mf * 16 + g * 4;
#pragma unroll
      for (int r = 0; r < 4; ++r) {
        out[((size_t)(b * 512 + h * 128 + dbase + r)) * 1024 + qg3] = acc[u][mf][r] * linv;
      }
    }
  }
}

extern "C" void kernel_launch(void* const* d_in, const int* in_sizes, int n_in,
                              void* d_out, int out_size, void* d_ws, size_t ws_size,
                              hipStream_t stream) {
  const float* fm = (const float*)d_in[0];
  const float* wqk = (const float*)d_in[1];
  const float* wv = (const float*)d_in[2];
  const float* relh = (const float*)d_in[3];
  const float* relw = (const float*)d_in[4];
  float* out = (float*)d_out;
  char* w = (char*)d_ws;

  __hip_bfloat16* fmt = (__hip_bfloat16*)w;                   // 16 MB  [B][L][C]
  __hip_bfloat16* wall = (__hip_bfloat16*)(w + 16777216);     // 1.5 MB [1536][512]
  __hip_bfloat16* Qb = (__hip_bfloat16*)(w + 18350080);       // 16 MB  [B][H][L][D] (scaled*log2e)
  __hip_bfloat16* Kb = (__hip_bfloat16*)(w + 35127296);       // 16 MB  [B][H][L][D]
  __hip_bfloat16* Vt = (__hip_bfloat16*)(w + 51904512);       // 16 MB  [B][H][D][L]
  float* QRW = (float*)(w + 68681728);                        // 16 MB  [B][H][L][64]
  float* QRH = (float*)(w + 85458944);                        // 16 MB  [B][H][L][64]
  __hip_bfloat16* relsb = (__hip_bfloat16*)(w + 102236160);   // 32 KB  [2][64][128]

  k_convw<<<3136, 256, 0, stream>>>(wqk, wv, relw, relh, wall, relsb);
  k_tfm<<<dim3(16, 8, 16), 256, 0, stream>>>(fm, fmt);
  k_gemm<<<dim3(8, 12, 16), 256, 0, stream>>>(fmt, wall, Qb, Kb, Vt);
  k_bias<<<dim3(8, 64), 256, 0, stream>>>(Qb, relsb, QRW, QRH);
  k_attn<<<dim3(8, 64), 256, 69632, stream>>>(Qb, Kb, Vt, QRW, QRH, out);
}

// Round 10
// 125.251 us; speedup vs baseline: 2.6590x; 1.0549x over previous
//
#include <hip/hip_runtime.h>
#include <hip/hip_bf16.h>
#include <math.h>

typedef __bf16 bf16x8 __attribute__((ext_vector_type(8)));
typedef float f32x4 __attribute__((ext_vector_type(4)));

// QSCALE * log2(e): Q (and the bias tables derived from Q) live in the exp2
// domain, so softmax needs only exp2f.
#define QSCALE_L2E (0.08838834764831845f * 1.4426950408889634f)

static __device__ __forceinline__ unsigned short bits_bf16(float v) {
  __hip_bfloat16 h = __float2bfloat16(v);
  return *reinterpret_cast<unsigned short*>(&h);
}

// async global->LDS DMA, 16B per lane; LDS dest = wave-uniform base + lane*16
static __device__ __forceinline__ void gload16(const void* g, void* l) {
  __builtin_amdgcn_global_load_lds(
      (const __attribute__((address_space(1))) void*)g,
      (__attribute__((address_space(3))) void*)l, 16, 0, 0);
}

// ---------------- kernel 1: convert weights + rel tables to bf16 ----------------
__global__ __launch_bounds__(256) void k_convw(const float* __restrict__ wqk,
                                               const float* __restrict__ wv,
                                               const float* __restrict__ relw,
                                               const float* __restrict__ relh,
                                               __hip_bfloat16* __restrict__ wall,
                                               __hip_bfloat16* __restrict__ relsb) {
  int i = blockIdx.x * 256 + threadIdx.x;
  if (i < 1536 * 512) {
    float v = (i < 1024 * 512) ? wqk[i] : wv[i - 1024 * 512];
    wall[i] = __float2bfloat16(v);
  } else {
    int j = i - 1536 * 512;  // 0..16383 : [2][64][128], row 63 of each table = 0
    int t = j >> 13, m = (j >> 7) & 63, d = j & 127;
    float v = (m < 63) ? (t ? relh[m * 128 + d] : relw[m * 128 + d]) : 0.f;
    relsb[j] = __float2bfloat16(v);
  }
}

// ---------------- kernel 2: transpose + convert featuremap -> [B][L][C] bf16 ----------------
__global__ __launch_bounds__(256) void k_tfm(const float* __restrict__ fm,
                                             __hip_bfloat16* __restrict__ fmt) {
  __shared__ float t[64][65];
  int lt = blockIdx.x, ct = blockIdx.y, b = blockIdx.z;
  int tid = threadIdx.x;
  const float* src = fm + ((size_t)b * 512 + ct * 64) * 1024 + lt * 64;
#pragma unroll
  for (int i = 0; i < 16; ++i) {
    int idx = i * 256 + tid;
    int r = idx >> 6, cl = idx & 63;
    t[r][cl] = src[(size_t)r * 1024 + cl];
  }
  __syncthreads();
  __hip_bfloat16* dst = fmt + ((size_t)b * 1024 + lt * 64) * 512 + ct * 64;
#pragma unroll
  for (int i = 0; i < 16; ++i) {
    int idx = i * 256 + tid;
    int r = idx >> 6, cc = idx & 63;
    dst[(size_t)r * 512 + cc] = __float2bfloat16(t[cc][r]);
  }
}

// ---------------- kernel 3: QKV projection GEMM (m97 structure) ----------------
__global__ __launch_bounds__(256) void k_gemm(const __hip_bfloat16* __restrict__ fmt,
                                              const __hip_bfloat16* __restrict__ wall,
                                              __hip_bfloat16* __restrict__ Qb,
                                              __hip_bfloat16* __restrict__ Kb,
                                              __hip_bfloat16* __restrict__ Vt) {
  __shared__ char smem[32768];
  char* As = smem;
  char* Bs = smem + 16384;
  int bm = blockIdx.x, bn = blockIdx.y, b = blockIdx.z;
  int tid = threadIdx.x;
  int lane = tid & 63, wave = tid >> 6;
  int wr = wave >> 1, wc = wave & 1;
  int g = lane >> 4, ln = lane & 15;
  const char* Ag = (const char*)(fmt + ((size_t)b * 1024 + bm * 128) * 512);
  const char* Bg = (const char*)(wall + (size_t)bn * 128 * 512);

  int j3 = lane >> 3, j7 = lane & 7;
  int segsrc = ((j7 ^ j3) << 4);  // pre-swizzled source seg (row&7 == j3)

  f32x4 acc[4][4] = {};
  for (int kb = 0; kb < 8; ++kb) {
#pragma unroll
    for (int i = 0; i < 4; ++i) {
      int R = (wave * 4 + i) * 8;  // 8 rows per 1KB DMA
      size_t go = (size_t)(R + j3) * 1024 + (size_t)kb * 128 + segsrc;
      gload16(Ag + go, As + R * 128);
      gload16(Bg + go, Bs + R * 128);
    }
    __syncthreads();
#pragma unroll
    for (int ks = 0; ks < 2; ++ks) {
      int kcol = ks * 64 + (g << 4);
      bf16x8 af[4], bfr[4];
#pragma unroll
      for (int m = 0; m < 4; ++m) {
        int row = wr * 64 + m * 16 + ln;
        af[m] = *(const bf16x8*)(As + row * 128 + (kcol ^ ((ln & 7) << 4)));
      }
#pragma unroll
      for (int n = 0; n < 4; ++n) {
        int row = wc * 64 + n * 16 + ln;
        bfr[n] = *(const bf16x8*)(Bs + row * 128 + (kcol ^ ((ln & 7) << 4)));
      }
#pragma unroll
      for (int m = 0; m < 4; ++m)
#pragma unroll
        for (int n = 0; n < 4; ++n)
          acc[m][n] = __builtin_amdgcn_mfma_f32_16x16x32_bf16(af[m], bfr[n], acc[m][n], 0, 0, 0);
    }
    __syncthreads();
  }

  // ---- epilogue: restage C tile in LDS, then coalesced row stores ----
  int otype = bn >> 2;  // 0=q, 1=k, 2=v
  int head = bn & 3;
  if (otype != 2) {
    float sc = (otype == 0) ? QSCALE_L2E : 1.0f;
#pragma unroll
    for (int m = 0; m < 4; ++m)
#pragma unroll
      for (int n = 0; n < 4; ++n) {
        int d = wc * 64 + n * 16 + ln;
#pragma unroll
        for (int r = 0; r < 4; ++r) {
          int l = wr * 64 + m * 16 + g * 4 + r;
          *(__hip_bfloat16*)(smem + l * 256 + ((d * 2) ^ ((l & 7) << 4))) =
              __float2bfloat16(acc[m][n][r] * sc);
        }
      }
    __syncthreads();
    __hip_bfloat16* dstb =
        (otype == 0 ? Qb : Kb) + (((size_t)(b * 4 + head) * 1024) + bm * 128) * 128;
#pragma unroll
    for (int i = 0; i < 8; ++i) {
      int idx = i * 256 + tid;
      int row = idx >> 4, c16 = idx & 15;
      uint4 v = *(const uint4*)(smem + row * 256 + ((c16 * 16) ^ ((row & 7) << 4)));
      *(uint4*)(dstb + (size_t)row * 128 + c16 * 8) = v;
    }
  } else {
#pragma unroll
    for (int m = 0; m < 4; ++m)
#pragma unroll
      for (int n = 0; n < 4; ++n) {
        int d = wc * 64 + n * 16 + ln;
        int lbase = wr * 64 + m * 16 + g * 4;
        ushort4 pk;
        pk.x = bits_bf16(acc[m][n][0]);
        pk.y = bits_bf16(acc[m][n][1]);
        pk.z = bits_bf16(acc[m][n][2]);
        pk.w = bits_bf16(acc[m][n][3]);
        *(ushort4*)(smem + d * 256 + ((lbase * 2) ^ ((d & 7) << 4))) = pk;
      }
    __syncthreads();
    __hip_bfloat16* dstb = Vt + ((size_t)(b * 4 + head) * 128) * 1024 + bm * 128;
#pragma unroll
    for (int i = 0; i < 8; ++i) {
      int idx = i * 256 + tid;
      int row = idx >> 4, c16 = idx & 15;
      uint4 v = *(const uint4*)(smem + row * 256 + ((c16 * 16) ^ ((row & 7) << 4)));
      *(uint4*)(dstb + (size_t)row * 1024 + c16 * 8) = v;
    }
  }
}

// ---------------- kernel 4: bias tables via MFMA ----------------
// Tables inherit the log2e factor from Qb automatically.
__global__ __launch_bounds__(256) void k_bias(const __hip_bfloat16* __restrict__ Qb,
                                              const __hip_bfloat16* __restrict__ relsb,
                                              float* __restrict__ QRW,
                                              float* __restrict__ QRH) {
  __shared__ char sh[32768];  // [2][64][128] bf16, swizzled
  int bx = blockIdx.x, bh = blockIdx.y;
  int tid = threadIdx.x, lane = tid & 63, wave = tid >> 6;
  int g = lane >> 4, ln = lane & 15;
#pragma unroll
  for (int i = 0; i < 8; ++i) {
    int chunk = i * 256 + tid;
    int row = chunk >> 4, c16 = chunk & 15;
    *(uint4*)(sh + row * 256 + ((c16 * 16) ^ ((row & 7) << 4))) =
        *(const uint4*)(relsb + (size_t)row * 128 + c16 * 8);
  }
  __syncthreads();
  size_t bhL = (size_t)bh * 1024;
  int l0 = bx * 128 + wave * 32;
  const __hip_bfloat16* Qg = Qb + (bhL + l0) * 128;
  bf16x8 a[2][4];
#pragma unroll
  for (int lf = 0; lf < 2; ++lf)
#pragma unroll
    for (int ks = 0; ks < 4; ++ks)
      a[lf][ks] = *(const bf16x8*)(Qg + (size_t)(lf * 16 + ln) * 128 + ks * 32 + g * 8);
#pragma unroll
  for (int t = 0; t < 2; ++t) {
    float* dst = (t == 0 ? QRW : QRH) + (bhL + l0) * 64;
#pragma unroll
    for (int n = 0; n < 4; ++n) {
      f32x4 acc2[2] = {};
#pragma unroll
      for (int ks = 0; ks < 4; ++ks) {
        int mrow = n * 16 + ln;
        bf16x8 bf = *(const bf16x8*)(sh + t * 16384 + mrow * 256 +
                                     ((ks * 64 + g * 16) ^ ((mrow & 7) << 4)));
#pragma unroll
        for (int lf = 0; lf < 2; ++lf)
          acc2[lf] = __builtin_amdgcn_mfma_f32_16x16x32_bf16(a[lf][ks], bf, acc2[lf], 0, 0, 0);
      }
#pragma unroll
      for (int lf = 0; lf < 2; ++lf)
#pragma unroll
        for (int r = 0; r < 4; ++r)
          dst[(size_t)(lf * 16 + g * 4 + r) * 64 + n * 16 + ln] = acc2[lf][r];
    }
  }
}

// ---------------- kernel 5: fused attention (8 waves, 256 q/block, K/V dbuf 2-phase) ----------------
// Swapped QK^T + 2 q-sets/wave (r9-verified core). Double-buffered K/V staged
// via global_load_lds with the stage for tile t+1 issued BEFORE computing tile
// t; single barrier per kt hides HBM latency under compute (T3-minimal).
__global__ __launch_bounds__(512, 2) void k_attn(const __hip_bfloat16* __restrict__ Qb,
                                                 const __hip_bfloat16* __restrict__ Kb,
                                                 const __hip_bfloat16* __restrict__ Vt,
                                                 const float* __restrict__ QRW,
                                                 const float* __restrict__ QRH,
                                                 float* __restrict__ out) {
  extern __shared__ char smem[];
  float* hb_s = (float*)smem;                 // [256][40] f32 = 40960 B
  char* kbuf = smem + 40960;                  // K dbuf [2][64][256B] = 32768 B
  char* vbuf = smem + 40960 + 32768;          // V dbuf [2][128][128B] = 32768 B
  char* pt = smem + 40960 + 65536;            // P [8 waves][32][128B] = 32768 B
                                              // total 139264 B

  int bh = blockIdx.x, qt = blockIdx.y;  // same-bh blocks differ by 64 in linear id -> same XCD
  int b = bh >> 2, h = bh & 3;
  int tid = threadIdx.x, lane = tid & 63, wave = tid >> 6;  // wave 0..7
  int g = lane >> 4, ln = lane & 15;
  int q0 = qt * 256;
  size_t bhL = (size_t)bh * 1024;

  // stage hb rows: aligned 36-float window of QRH per q-row (start = (31-rx)&~3)
#pragma unroll
  for (int i = 0; i < 5; ++i) {
    int c = i * 512 + tid;  // 256 rows x 9 chunks = 2304
    if (c < 2304) {
      int row = c / 9, j = c % 9;
      int s0 = (31 - ((q0 + row) >> 5)) & ~3;
      *(uint4*)(hb_s + row * 40 + j * 4) =
          *(const uint4*)(QRH + (bhL + q0 + row) * 64 + s0 + j * 4);
    }
  }

  // per-q-set constants + direct global->reg loads (one-time)
  bf16x8 qa[2][4];
  float wb[2][2][4];
  int qloc[2], hbase[2];
#pragma unroll
  for (int u = 0; u < 2; ++u) {
    qloc[u] = wave * 32 + u * 16 + ln;
    int qg = q0 + qloc[u];
    int cx = qg & 31, rx = qg >> 5;
    hbase[u] = (31 - rx) & 3;
    const __hip_bfloat16* qrow = Qb + (bhL + qg) * 128;
#pragma unroll
    for (int ks = 0; ks < 4; ++ks)
      qa[u][ks] = *(const bf16x8*)(qrow + ks * 32 + g * 8);
    const float* wrow = QRW + (bhL + qg) * 64 + (31 - cx) + g * 4;
#pragma unroll
    for (int half = 0; half < 2; ++half)
#pragma unroll
      for (int r = 0; r < 4; ++r) wb[u][half][r] = wrow[half * 16 + r];
  }

  const char* Kg0 = (const char*)(Kb + bhL * 128);
  const char* Vg0 = (const char*)(Vt + (size_t)bh * 128 * 1024);
  int j3 = lane >> 3, j7 = lane & 7;
  int segv = ((j7 ^ j3) << 4);

  // stage K/V tile kt2 into buffer bsel (2 gload16 each per wave)
  auto STAGE = [&](int bsel, int kt2) {
    const char* Kg = Kg0 + (size_t)kt2 * 64 * 256;
    char* kvb = kbuf + bsel * 16384;
#pragma unroll
    for (int i = 0; i < 2; ++i) {
      int R = (wave * 2 + i) * 4;  // chunk parity = i
      int seg = ((lane & 15) ^ ((i & 1) * 4 + (lane >> 4))) << 4;
      gload16(Kg + (size_t)(R + (lane >> 4)) * 256 + seg, kvb + R * 256);
    }
    const char* Vg = Vg0 + (size_t)kt2 * 128;
    char* vtb = vbuf + bsel * 16384;
#pragma unroll
    for (int i = 0; i < 2; ++i) {
      int R = (wave * 2 + i) * 8;
      gload16(Vg + (size_t)(R + j3) * 2048 + segv, vtb + R * 128);
    }
  };

  f32x4 acc[2][8] = {};
  float mrow[2] = {-1e30f, -1e30f}, lrow[2] = {0.f, 0.f};
  char* pw = pt + wave * 4096;

  STAGE(0, 0);
  __syncthreads();  // drains prologue stage + hb_s writes

  for (int kt = 0; kt < 16; ++kt) {
    int cur = kt & 1;
    if (kt < 15) STAGE(cur ^ 1, kt + 1);  // issue next tile early; drained at barrier below
    char* kvb = kbuf + cur * 16384;
    char* vtb = vbuf + cur * 16384;

    // S^T = K Q^T (log2 domain): s[u][n][r] = S[key=n*16+g*4+r][q=qloc[u]]
    f32x4 s[2][4] = {};
    __builtin_amdgcn_s_setprio(1);
#pragma unroll
    for (int ks = 0; ks < 4; ++ks) {
      int kcol = ks * 64 + (g << 4);
#pragma unroll
      for (int n = 0; n < 4; ++n) {
        int krow = n * 16 + ln;
        bf16x8 kf = *(const bf16x8*)(kvb + krow * 256 + (kcol ^ ((krow & 7) << 4)));
        s[0][n] = __builtin_amdgcn_mfma_f32_16x16x32_bf16(kf, qa[0][ks], s[0][n], 0, 0, 0);
        s[1][n] = __builtin_amdgcn_mfma_f32_16x16x32_bf16(kf, qa[1][ks], s[1][n], 0, 0, 0);
      }
    }
    __builtin_amdgcn_s_setprio(0);
    // bias + online softmax + P write, per q-set
#pragma unroll
    for (int u = 0; u < 2; ++u) {
      float hb0 = hb_s[qloc[u] * 40 + hbase[u] + kt * 2];
      float hb1 = hb_s[qloc[u] * 40 + hbase[u] + kt * 2 + 1];
#pragma unroll
      for (int n = 0; n < 4; ++n) {
        float hb = (n >> 1) ? hb1 : hb0;
#pragma unroll
        for (int r = 0; r < 4; ++r) s[u][n][r] += wb[u][n & 1][r] + hb;
      }
      float mt = s[u][0][0];
#pragma unroll
      for (int n = 0; n < 4; ++n)
#pragma unroll
        for (int r = 0; r < 4; ++r) mt = fmaxf(mt, s[u][n][r]);
      mt = fmaxf(mt, __shfl_xor(mt, 16, 64));
      mt = fmaxf(mt, __shfl_xor(mt, 32, 64));
      float mn = fmaxf(mrow[u], mt);
      float alpha = exp2f(mrow[u] - mn);
      mrow[u] = mn;
      float rs = 0.f;
#pragma unroll
      for (int n = 0; n < 4; ++n)
#pragma unroll
        for (int r = 0; r < 4; ++r) {
          s[u][n][r] = exp2f(s[u][n][r] - mn);
          rs += s[u][n][r];
        }
      rs += __shfl_xor(rs, 16, 64);
      rs += __shfl_xor(rs, 32, 64);
      lrow[u] = lrow[u] * alpha + rs;
#pragma unroll
      for (int mf = 0; mf < 8; ++mf) acc[u][mf] *= alpha;
#pragma unroll
      for (int n = 0; n < 4; ++n) {
        ushort4 pk;
        pk.x = bits_bf16(s[u][n][0]);
        pk.y = bits_bf16(s[u][n][1]);
        pk.z = bits_bf16(s[u][n][2]);
        pk.w = bits_bf16(s[u][n][3]);
        *(ushort4*)(pw + (u * 16 + ln) * 128 + ((n * 32 + g * 8) ^ ((ln & 7) << 4))) = pk;
      }
    }
    // PV (transposed): acc[u][d][q] += V_t . P^T ; av shared across both q-sets
    __builtin_amdgcn_s_setprio(1);
#pragma unroll
    for (int ks2 = 0; ks2 < 2; ++ks2) {
      int kcb = ks2 * 64 + (g << 4);
      bf16x8 pb0 = *(const bf16x8*)(pw + ln * 128 + (kcb ^ ((ln & 7) << 4)));
      bf16x8 pb1 = *(const bf16x8*)(pw + (16 + ln) * 128 + (kcb ^ ((ln & 7) << 4)));
#pragma unroll
      for (int mf = 0; mf < 8; ++mf) {
        int vrow = mf * 16 + ln;
        bf16x8 av = *(const bf16x8*)(vtb + vrow * 128 + (kcb ^ ((vrow & 7) << 4)));
        acc[0][mf] = __builtin_amdgcn_mfma_f32_16x16x32_bf16(av, pb0, acc[0][mf], 0, 0, 0);
        acc[1][mf] = __builtin_amdgcn_mfma_f32_16x16x32_bf16(av, pb1, acc[1][mf], 0, 0, 0);
      }
    }
    __builtin_amdgcn_s_setprio(0);
    __syncthreads();  // drains next-tile stage; releases cur buffer for overwrite
  }
  // normalize + store (l and acc columns are in-lane per q-set)
#pragma unroll
  for (int u = 0; u < 2; ++u) {
    float linv = 1.0f / lrow[u];
    int qg3 = q0 + wave * 32 + u * 16 + ln;
#pragma unroll
    for (int mf = 0; mf < 8; ++mf) {
      int dbase = mf * 16 + g * 4;
#pragma unroll
      for (int r = 0; r < 4; ++r) {
        out[((size_t)(b * 512 + h * 128 + dbase + r)) * 1024 + qg3] = acc[u][mf][r] * linv;
      }
    }
  }
}

extern "C" void kernel_launch(void* const* d_in, const int* in_sizes, int n_in,
                              void* d_out, int out_size, void* d_ws, size_t ws_size,
                              hipStream_t stream) {
  const float* fm = (const float*)d_in[0];
  const float* wqk = (const float*)d_in[1];
  const float* wv = (const float*)d_in[2];
  const float* relh = (const float*)d_in[3];
  const float* relw = (const float*)d_in[4];
  float* out = (float*)d_out;
  char* w = (char*)d_ws;

  __hip_bfloat16* fmt = (__hip_bfloat16*)w;                   // 16 MB  [B][L][C]
  __hip_bfloat16* wall = (__hip_bfloat16*)(w + 16777216);     // 1.5 MB [1536][512]
  __hip_bfloat16* Qb = (__hip_bfloat16*)(w + 18350080);       // 16 MB  [B][H][L][D] (scaled*log2e)
  __hip_bfloat16* Kb = (__hip_bfloat16*)(w + 35127296);       // 16 MB  [B][H][L][D]
  __hip_bfloat16* Vt = (__hip_bfloat16*)(w + 51904512);       // 16 MB  [B][H][D][L]
  float* QRW = (float*)(w + 68681728);                        // 16 MB  [B][H][L][64]
  float* QRH = (float*)(w + 85458944);                        // 16 MB  [B][H][L][64]
  __hip_bfloat16* relsb = (__hip_bfloat16*)(w + 102236160);   // 32 KB  [2][64][128]

  hipFuncSetAttribute((const void*)k_attn,
                      hipFuncAttributeMaxDynamicSharedMemorySize, 139264);

  k_convw<<<3136, 256, 0, stream>>>(wqk, wv, relw, relh, wall, relsb);
  k_tfm<<<dim3(16, 8, 16), 256, 0, stream>>>(fm, fmt);
  k_gemm<<<dim3(8, 12, 16), 256, 0, stream>>>(fmt, wall, Qb, Kb, Vt);
  k_bias<<<dim3(8, 64), 256, 0, stream>>>(Qb, relsb, QRW, QRH);
  k_attn<<<dim3(64, 4), 512, 139264, stream>>>(Qb, Kb, Vt, QRW, QRH, out);
}